// Round 1
// 13990.361 us; speedup vs baseline: 3.1201x; 3.1201x over previous
//
#include <hip/hip_runtime.h>
#include <math.h>

// Problem constants
constexpr int B_ = 2, S_ = 1024, D_ = 2048, H_ = 16;
constexpr int NOPE_ = 128, ROPE_ = 64, VD_ = 128, KVR_ = 512, QLR_ = 1536;
constexpr int NE_ = 16, MI_ = 1408, SMI_ = 2816;
constexpr int QKD_ = NOPE_ + ROPE_;            // 192
constexpr int T_ = B_ * S_;                    // 2048
constexpr float SCALE_ = 0.07216878364870322f; // 192^-0.5
constexpr float EPS_ = 1e-3f;
constexpr int MAX_TILES_ = 80;                 // sum_e ceil(n_e/64) <= 79

// ---------------------------------------------------------------------------
// Generic tiled fp32 GEMM: C[M,N] = A[M,K] @ W^T + bias + residual
// W layout: w_kn==0 -> W[N,K] row-major (ld=ldw over K)
//           w_kn==1 -> W[K,N] row-major (ld=ldw over N)   (i.e. plain A@W)
// Batched via blockIdx.z with element strides. All dims divide tile sizes
// (M%64==0, N%64==0, K%16==0 for every call below) -> no bounds checks.
// ---------------------------------------------------------------------------
__global__ __launch_bounds__(256) void gemm_kernel(
    const float* __restrict__ A, int lda, long strideA,
    const float* __restrict__ W, int ldw, long strideW, int w_kn,
    const float* __restrict__ bias, long strideBias,
    const float* __restrict__ res, int ldr, long strideRes,
    float* __restrict__ C, int ldc, long strideC,
    int M, int N, int K)
{
    (void)M;
    const int bz = blockIdx.z;
    A += (long)bz * strideA;
    W += (long)bz * strideW;
    C += (long)bz * strideC;
    if (bias) bias += (long)bz * strideBias;
    if (res)  res  += (long)bz * strideRes;

    __shared__ float As[16][68];
    __shared__ float Ws[16][68];

    const int m0 = blockIdx.y * 64;
    const int n0 = blockIdx.x * 64;
    const int tid = threadIdx.x;
    const int tx = tid & 15;   // 0..15 -> N micro
    const int ty = tid >> 4;   // 0..15 -> M micro

    float acc[4][4] = {};

    for (int kt = 0; kt < K; kt += 16) {
        #pragma unroll
        for (int i = 0; i < 4; i++) {
            int p = tid + i * 256;
            int r = p >> 4, kk = p & 15;
            As[kk][r] = A[(long)(m0 + r) * lda + (kt + kk)];
        }
        if (w_kn) {
            #pragma unroll
            for (int i = 0; i < 4; i++) {
                int p = tid + i * 256;
                int kk = p >> 6, n = p & 63;
                Ws[kk][n] = W[(long)(kt + kk) * ldw + (n0 + n)];
            }
        } else {
            #pragma unroll
            for (int i = 0; i < 4; i++) {
                int p = tid + i * 256;
                int n = p >> 4, kk = p & 15;
                Ws[kk][n] = W[(long)(n0 + n) * ldw + (kt + kk)];
            }
        }
        __syncthreads();
        #pragma unroll
        for (int kk = 0; kk < 16; kk++) {
            float a[4], b[4];
            #pragma unroll
            for (int i = 0; i < 4; i++) a[i] = As[kk][ty * 4 + i];
            #pragma unroll
            for (int j = 0; j < 4; j++) b[j] = Ws[kk][tx * 4 + j];
            #pragma unroll
            for (int i = 0; i < 4; i++)
                #pragma unroll
                for (int j = 0; j < 4; j++)
                    acc[i][j] += a[i] * b[j];
        }
        __syncthreads();
    }

    #pragma unroll
    for (int i = 0; i < 4; i++) {
        int m = m0 + ty * 4 + i;
        #pragma unroll
        for (int j = 0; j < 4; j++) {
            int n = n0 + tx * 4 + j;
            float v = acc[i][j];
            if (bias) v += bias[n];
            if (res)  v += res[(long)m * ldr + n];
            C[(long)m * ldc + n] = v;
        }
    }
}

// ---------------------------------------------------------------------------
// RMSNorm over rows: out = w * x * rsqrt(mean(x^2)+eps). In-place safe.
// ---------------------------------------------------------------------------
__global__ __launch_bounds__(256) void rms_kernel(
    const float* __restrict__ in, float* __restrict__ out,
    const float* __restrict__ w, int N, int in_stride, int out_stride)
{
    const int row = blockIdx.x;
    const float* x = in + (long)row * in_stride;
    float* y = out + (long)row * out_stride;
    __shared__ float red[256];
    const int tid = threadIdx.x;
    float s = 0.f;
    for (int i = tid; i < N; i += 256) { float v = x[i]; s += v * v; }
    red[tid] = s; __syncthreads();
    for (int st = 128; st > 0; st >>= 1) {
        if (tid < st) red[tid] += red[tid + st];
        __syncthreads();
    }
    const float scale = rsqrtf(red[0] / (float)N + EPS_);
    for (int i = tid; i < N; i += 256) y[i] = w[i] * x[i] * scale;
}

// ---------------------------------------------------------------------------
// Interleaved RoPE, in place. pos = token % S_.
// ---------------------------------------------------------------------------
__global__ void rope_kernel(float* __restrict__ p,
                            const float* __restrict__ cosb,
                            const float* __restrict__ sinb,
                            int nheads, int row_stride, int head_stride,
                            int off, int total)
{
    int i = blockIdx.x * 256 + threadIdx.x;
    if (i >= total) return;
    int pair = i & 31;
    int rem = i >> 5;
    int h = rem % nheads;
    int t = rem / nheads;
    int s = t % S_;
    float c = cosb[s * 32 + pair], sn = sinb[s * 32 + pair];
    float* base = p + (long)t * row_stride + (long)h * head_stride + off + pair * 2;
    float x0 = base[0], x1 = base[1];
    base[0] = x0 * c - x1 * sn;
    base[1] = x0 * sn + x1 * c;
}

// ---------------------------------------------------------------------------
// Attention: one block per (s, h, b). q_abs row in, o row out (same buffer).
// kvf rows: [kv_n(512) | k_pe(64)], stride 576. Full (non-causal) softmax.
// ---------------------------------------------------------------------------
__global__ __launch_bounds__(256) void attn_kernel(
    const float* __restrict__ q,    // [T, H, 192]
    const float* __restrict__ kvf,  // [T, 576]
    float* __restrict__ qabs_o)     // [T, H, 512] (in: q_abs, out: o)
{
    const int s = blockIdx.x, h = blockIdx.y, b = blockIdx.z;
    const long row = (long)(b * S_ + s) * H_ + h;
    const int t0 = b * S_;

    __shared__ float qa_l[512];
    __shared__ float qp_l[64];
    __shared__ float sc[1024];
    __shared__ float red[256];

    const int tid = threadIdx.x;
    const float* qabs_row = qabs_o + row * 512;
    for (int c = tid; c < 512; c += 256) qa_l[c] = qabs_row[c];
    const float* q_row = q + row * 192 + 128;
    if (tid < 64) qp_l[tid] = q_row[tid];
    __syncthreads();

    for (int t = tid; t < S_; t += 256) {
        const float4* kv4 = (const float4*)(kvf + (long)(t0 + t) * 576);
        float acc = 0.f;
        #pragma unroll 4
        for (int c = 0; c < 128; c++) {
            float4 k = kv4[c];
            acc += qa_l[c * 4 + 0] * k.x + qa_l[c * 4 + 1] * k.y +
                   qa_l[c * 4 + 2] * k.z + qa_l[c * 4 + 3] * k.w;
        }
        #pragma unroll 4
        for (int r = 0; r < 16; r++) {
            float4 k = kv4[128 + r];
            acc += qp_l[r * 4 + 0] * k.x + qp_l[r * 4 + 1] * k.y +
                   qp_l[r * 4 + 2] * k.z + qp_l[r * 4 + 3] * k.w;
        }
        sc[t] = acc * SCALE_;
    }
    __syncthreads();

    float m = -1e30f;
    for (int t = tid; t < S_; t += 256) m = fmaxf(m, sc[t]);
    red[tid] = m; __syncthreads();
    for (int st = 128; st > 0; st >>= 1) {
        if (tid < st) red[tid] = fmaxf(red[tid], red[tid + st]);
        __syncthreads();
    }
    m = red[0];
    __syncthreads();

    float sum = 0.f;
    for (int t = tid; t < S_; t += 256) {
        float e = __expf(sc[t] - m);
        sc[t] = e;
        sum += e;
    }
    red[tid] = sum; __syncthreads();
    for (int st = 128; st > 0; st >>= 1) {
        if (tid < st) red[tid] += red[tid + st];
        __syncthreads();
    }
    const float inv = 1.f / red[0];
    __syncthreads();
    for (int t = tid; t < S_; t += 256) sc[t] *= inv;
    __syncthreads();

    float* o_row = qabs_o + row * 512;
    for (int c = tid; c < 512; c += 256) {
        float acc = 0.f;
        const float* kv = kvf + (long)t0 * 576 + c;
        for (int t = 0; t < S_; t++) acc += sc[t] * kv[(long)t * 576];
        o_row[c] = acc;
    }
}

// ---------------------------------------------------------------------------
// Gate: logits -> softmax -> top2 on (probs + gate_b), weights = probs[idx]
// ---------------------------------------------------------------------------
__global__ __launch_bounds__(256) void gate_kernel(
    const float* __restrict__ h2, const float* __restrict__ gw,
    const float* __restrict__ gb, int* __restrict__ idx,
    float* __restrict__ wts)
{
    const int t = blockIdx.x;
    __shared__ float red[256];
    __shared__ float logits[16];
    const int tid = threadIdx.x;
    const int e = tid >> 4, lane = tid & 15;
    const float* x = h2 + (long)t * 2048;
    float s = 0.f;
    for (int i = lane; i < 2048; i += 16) s += x[i] * gw[e * 2048 + i];
    red[tid] = s; __syncthreads();
    for (int st = 8; st > 0; st >>= 1) {
        if (lane < st) red[tid] += red[tid + st];
        __syncthreads();
    }
    if (lane == 0) logits[e] = red[e * 16] + gb[e];
    __syncthreads();
    if (tid == 0) {
        float m = logits[0];
        for (int j = 1; j < 16; j++) m = fmaxf(m, logits[j]);
        float pr[16]; float sum = 0.f;
        for (int j = 0; j < 16; j++) { pr[j] = expf(logits[j] - m); sum += pr[j]; }
        float inv = 1.f / sum;
        for (int j = 0; j < 16; j++) pr[j] *= inv;
        int i1 = 0; float v1 = -1e30f;
        for (int j = 0; j < 16; j++) { float v = pr[j] + gb[j]; if (v > v1) { v1 = v; i1 = j; } }
        int i2 = 0; float v2 = -1e30f;
        for (int j = 0; j < 16; j++) { if (j == i1) continue; float v = pr[j] + gb[j]; if (v > v2) { v2 = v; i2 = j; } }
        idx[t * 2 + 0] = i1; idx[t * 2 + 1] = i2;
        wts[t * 2 + 0] = pr[i1]; wts[t * 2 + 1] = pr[i2];
    }
}

// ---------------------------------------------------------------------------
// Route: sort the 2T (token, k) assignments by expert (counting sort) and
// emit a tile map: tiles of up to 64 consecutive slots of the same expert.
// slot_te[pos*2] = (t<<1)|k ; slot_te[pos*2+1] = e ; slot_w[pos] = weight
// ---------------------------------------------------------------------------
__global__ __launch_bounds__(256) void route_kernel(
    const int* __restrict__ idx, const float* __restrict__ wts,
    int* __restrict__ slot_te, float* __restrict__ slot_w,
    int* __restrict__ tile_e, int* __restrict__ tile_row0,
    int* __restrict__ tile_cnt, int* __restrict__ n_tiles)
{
    __shared__ int counts[16], offs[16], cursor[16];
    const int tid = threadIdx.x;
    if (tid < 16) { counts[tid] = 0; cursor[tid] = 0; }
    __syncthreads();
    for (int a = tid; a < 2 * T_; a += 256) atomicAdd(&counts[idx[a]], 1);
    __syncthreads();
    if (tid == 0) {
        int o = 0;
        for (int e = 0; e < 16; e++) { offs[e] = o; o += counts[e]; }
        // tile map
        int nt = 0;
        for (int e = 0; e < 16; e++) {
            for (int r0 = 0; r0 < counts[e]; r0 += 64) {
                tile_e[nt] = e;
                tile_row0[nt] = offs[e] + r0;
                int c = counts[e] - r0;
                tile_cnt[nt] = c < 64 ? c : 64;
                nt++;
            }
        }
        *n_tiles = nt;
    }
    __syncthreads();
    for (int a = tid; a < 2 * T_; a += 256) {
        int e = idx[a];
        int pos = offs[e] + atomicAdd(&cursor[e], 1);
        int t = a >> 1, k = a & 1;
        slot_te[pos * 2 + 0] = (t << 1) | k;
        slot_te[pos * 2 + 1] = e;
        slot_w[pos] = wts[a];
    }
}

// ---------------------------------------------------------------------------
// MoE stage 1: batched per-expert GEMM. One block = 64 slots x 64 mi-cols.
// G[slot, i] = silu(x@W1^T + b1) * (x@W3^T + b3), x gathered from h2 by the
// routed token index. Grid: (MI/64, MAX_TILES); tiles >= n_tiles exit.
// ---------------------------------------------------------------------------
__global__ __launch_bounds__(256) void moe_mlp13_kernel(
    const float* __restrict__ h2,
    const int* __restrict__ slot_te,
    const int* __restrict__ tile_e, const int* __restrict__ tile_row0,
    const int* __restrict__ tile_cnt, const int* __restrict__ n_tiles,
    const float* __restrict__ w1, const float* __restrict__ b1,
    const float* __restrict__ w3, const float* __restrict__ b3,
    float* __restrict__ G)
{
    const int tile = blockIdx.y;
    if (tile >= *n_tiles) return;
    const int e    = tile_e[tile];
    const int row0 = tile_row0[tile];
    const int tcnt = tile_cnt[tile];
    const int n0   = blockIdx.x * 64;

    __shared__ float As[16][68];
    __shared__ float W1s[16][68];
    __shared__ float W3s[16][68];
    __shared__ int tok[64];

    const int tid = threadIdx.x;
    if (tid < 64) {
        int r = tid < tcnt ? tid : tcnt - 1;        // clamp padded rows
        tok[tid] = slot_te[(row0 + r) * 2 + 0] >> 1;
    }
    __syncthreads();

    const float* W1 = w1 + (long)e * MI_ * 2048;
    const float* W3 = w3 + (long)e * MI_ * 2048;

    const int tx = tid & 15, ty = tid >> 4;
    float acc1[4][4] = {}, acc3[4][4] = {};

    for (int kt = 0; kt < 2048; kt += 16) {
        #pragma unroll
        for (int i = 0; i < 4; i++) {
            int p = tid + i * 256;
            int r = p >> 4, kk = p & 15;
            As[kk][r] = h2[(long)tok[r] * 2048 + (kt + kk)];
        }
        #pragma unroll
        for (int i = 0; i < 4; i++) {
            int p = tid + i * 256;
            int n = p >> 4, kk = p & 15;
            W1s[kk][n] = W1[(long)(n0 + n) * 2048 + (kt + kk)];
            W3s[kk][n] = W3[(long)(n0 + n) * 2048 + (kt + kk)];
        }
        __syncthreads();
        #pragma unroll
        for (int kk = 0; kk < 16; kk++) {
            float a[4], b[4], c[4];
            #pragma unroll
            for (int i = 0; i < 4; i++) a[i] = As[kk][ty * 4 + i];
            #pragma unroll
            for (int j = 0; j < 4; j++) {
                b[j] = W1s[kk][tx * 4 + j];
                c[j] = W3s[kk][tx * 4 + j];
            }
            #pragma unroll
            for (int i = 0; i < 4; i++)
                #pragma unroll
                for (int j = 0; j < 4; j++) {
                    acc1[i][j] += a[i] * b[j];
                    acc3[i][j] += a[i] * c[j];
                }
        }
        __syncthreads();
    }

    #pragma unroll
    for (int i = 0; i < 4; i++) {
        int rl = ty * 4 + i;
        if (rl >= tcnt) continue;
        long grow = (long)(row0 + rl) * MI_;
        #pragma unroll
        for (int j = 0; j < 4; j++) {
            int n = n0 + tx * 4 + j;
            float a = acc1[i][j] + b1[e * MI_ + n];
            float b = acc3[i][j] + b3[e * MI_ + n];
            G[grow + n] = (a / (1.f + expf(-a))) * b;
        }
    }
}

// ---------------------------------------------------------------------------
// MoE stage 2: Y[slot, d] = wgt * (G[slot] @ W2[e]^T + b2[e]), scattered to
// y0/y1 by (t, k). Grid: (D/64, MAX_TILES).
// ---------------------------------------------------------------------------
__global__ __launch_bounds__(256) void moe_mlp2_kernel(
    const float* __restrict__ G,
    const int* __restrict__ slot_te, const float* __restrict__ slot_w,
    const int* __restrict__ tile_e, const int* __restrict__ tile_row0,
    const int* __restrict__ tile_cnt, const int* __restrict__ n_tiles,
    const float* __restrict__ w2, const float* __restrict__ b2,
    float* __restrict__ y0, float* __restrict__ y1)
{
    const int tile = blockIdx.y;
    if (tile >= *n_tiles) return;
    const int e    = tile_e[tile];
    const int row0 = tile_row0[tile];
    const int tcnt = tile_cnt[tile];
    const int n0   = blockIdx.x * 64;

    __shared__ float As[16][68];
    __shared__ float Ws[16][68];
    __shared__ int rsrc[64];

    const int tid = threadIdx.x;
    if (tid < 64) {
        int r = tid < tcnt ? tid : tcnt - 1;
        rsrc[tid] = row0 + r;
    }
    __syncthreads();

    const float* W2 = w2 + (long)e * 2048 * MI_;

    const int tx = tid & 15, ty = tid >> 4;
    float acc[4][4] = {};

    for (int kt = 0; kt < MI_; kt += 16) {
        #pragma unroll
        for (int i = 0; i < 4; i++) {
            int p = tid + i * 256;
            int r = p >> 4, kk = p & 15;
            As[kk][r] = G[(long)rsrc[r] * MI_ + (kt + kk)];
        }
        #pragma unroll
        for (int i = 0; i < 4; i++) {
            int p = tid + i * 256;
            int n = p >> 4, kk = p & 15;
            Ws[kk][n] = W2[(long)(n0 + n) * MI_ + (kt + kk)];
        }
        __syncthreads();
        #pragma unroll
        for (int kk = 0; kk < 16; kk++) {
            float a[4], b[4];
            #pragma unroll
            for (int i = 0; i < 4; i++) a[i] = As[kk][ty * 4 + i];
            #pragma unroll
            for (int j = 0; j < 4; j++) b[j] = Ws[kk][tx * 4 + j];
            #pragma unroll
            for (int i = 0; i < 4; i++)
                #pragma unroll
                for (int j = 0; j < 4; j++)
                    acc[i][j] += a[i] * b[j];
        }
        __syncthreads();
    }

    #pragma unroll
    for (int i = 0; i < 4; i++) {
        int rl = ty * 4 + i;
        if (rl >= tcnt) continue;
        int slot = row0 + rl;
        int tk = slot_te[slot * 2 + 0];
        int t = tk >> 1, k = tk & 1;
        float wgt = slot_w[slot];
        float* y = (k ? y1 : y0) + (long)t * 2048;
        #pragma unroll
        for (int j = 0; j < 4; j++) {
            int n = n0 + tx * 4 + j;
            y[n] = wgt * (acc[i][j] + b2[e * 2048 + n]);
        }
    }
}

// ---------------------------------------------------------------------------
// u1 = silu(u1) * u3
// ---------------------------------------------------------------------------
__global__ void silu_mul_kernel(float* __restrict__ u1,
                                const float* __restrict__ u3, long n)
{
    long i = (long)blockIdx.x * 256 + threadIdx.x;
    if (i >= n) return;
    float a = u1[i];
    u1[i] = (a / (1.f + expf(-a))) * u3[i];
}

// ---------------------------------------------------------------------------
// out = x2 + h2 + y0 + y1 + z
// ---------------------------------------------------------------------------
__global__ void final_add_kernel(const float* __restrict__ x2,
                                 const float* __restrict__ h2,
                                 const float* __restrict__ y0,
                                 const float* __restrict__ y1,
                                 const float* __restrict__ z,
                                 float* __restrict__ out, long n)
{
    long i = (long)blockIdx.x * 256 + threadIdx.x;
    if (i >= n) return;
    out[i] = x2[i] + h2[i] + y0[i] + y1[i] + z[i];
}

// ---------------------------------------------------------------------------
extern "C" void kernel_launch(void* const* d_in, const int* in_sizes, int n_in,
                              void* d_out, int out_size, void* d_ws, size_t ws_size,
                              hipStream_t stream)
{
    (void)in_sizes; (void)n_in; (void)out_size; (void)ws_size;

    const float* x          = (const float*)d_in[0];
    const float* attn_nw    = (const float*)d_in[1];
    const float* ffn_nw     = (const float*)d_in[2];
    const float* wq_a_w     = (const float*)d_in[3];
    const float* wq_a_b     = (const float*)d_in[4];
    const float* q_norm_w   = (const float*)d_in[5];
    const float* wq_b_w     = (const float*)d_in[6];
    const float* wq_b_b     = (const float*)d_in[7];
    const float* wkv_a_w    = (const float*)d_in[8];
    const float* wkv_a_b    = (const float*)d_in[9];
    const float* kv_norm_w  = (const float*)d_in[10];
    const float* wkv_b_w    = (const float*)d_in[11];
    const float* wo_w       = (const float*)d_in[12];
    const float* wo_b       = (const float*)d_in[13];
    const float* gate_w     = (const float*)d_in[14];
    const float* gate_b     = (const float*)d_in[15];
    const float* e_w1       = (const float*)d_in[16];
    const float* e_b1       = (const float*)d_in[17];
    const float* e_w2       = (const float*)d_in[18];
    const float* e_b2       = (const float*)d_in[19];
    const float* e_w3       = (const float*)d_in[20];
    const float* e_b3       = (const float*)d_in[21];
    const float* s_w1       = (const float*)d_in[22];
    const float* s_b1       = (const float*)d_in[23];
    const float* s_w2       = (const float*)d_in[24];
    const float* s_b2       = (const float*)d_in[25];
    const float* s_w3       = (const float*)d_in[26];
    const float* s_b3       = (const float*)d_in[27];
    const float* cosb       = (const float*)d_in[28];
    const float* sinb       = (const float*)d_in[29];

    float* ws = (float*)d_ws;
    // Workspace layout (floats)
    float* h    = ws + 0;            // T*2048          (reused later as y0)
    float* qa   = ws + 4194304;      // T*1536
    float* q    = ws + 7340032;      // T*3072          (reused later as y1)
    float* kvf  = ws + 13631488;     // T*576
    float* qabs = ws + 14811136;     // T*H*512 = 16.8M (q_abs, then o, then G)
    float* o2   = ws + 31588352;     // T*2048
    float* x2   = ws + 35782656;     // T*2048
    float* h2   = ws + 39976960;     // T*2048
    float* u1   = ws + 44171264;     // T*2816
    float* u3   = ws + 49938432;     // T*2816          (reused later as z)
    float* wts  = ws + 55705600;     // T*2 floats
    int*   idx  = (int*)(ws + 55709696);     // T*2 ints
    int*   slot_te = (int*)(ws + 55713792);  // 2T*2 ints
    float* slot_w  = ws + 55721984;          // 2T floats
    float* y0 = h;
    float* y1 = q;
    float* z  = u3;

    // MoE scratch inside the (dead after step 10) qabs region:
    float* G = qabs;                              // 2T * MI = 5,767,168 floats
    int* tile_e    = (int*)(qabs + 5767168);      // MAX_TILES
    int* tile_row0 = tile_e + MAX_TILES_;
    int* tile_cnt  = tile_e + 2 * MAX_TILES_;
    int* n_tiles   = tile_e + 3 * MAX_TILES_;

    // 1. h = rms(x, attn_norm_w)
    rms_kernel<<<dim3(T_), 256, 0, stream>>>(x, h, attn_nw, 2048, 2048, 2048);

    // 2. qa = h @ wq_a_w^T + wq_a_b            [T,1536]
    gemm_kernel<<<dim3(QLR_ / 64, T_ / 64, 1), 256, 0, stream>>>(
        h, 2048, 0, wq_a_w, 2048, 0, 0, wq_a_b, 0,
        nullptr, 0, 0, qa, QLR_, 0, T_, QLR_, 2048);

    // 3. qa = rms(qa, q_norm_w) in place
    rms_kernel<<<dim3(T_), 256, 0, stream>>>(qa, qa, q_norm_w, QLR_, QLR_, QLR_);

    // 4. q = qa @ wq_b_w^T + wq_b_b            [T, 3072]
    gemm_kernel<<<dim3(H_ * QKD_ / 64, T_ / 64, 1), 256, 0, stream>>>(
        qa, QLR_, 0, wq_b_w, QLR_, 0, 0, wq_b_b, 0,
        nullptr, 0, 0, q, H_ * QKD_, 0, T_, H_ * QKD_, QLR_);

    // 5. kvf = h @ wkv_a_w^T + wkv_a_b         [T, 576]
    gemm_kernel<<<dim3((KVR_ + ROPE_) / 64, T_ / 64, 1), 256, 0, stream>>>(
        h, 2048, 0, wkv_a_w, 2048, 0, 0, wkv_a_b, 0,
        nullptr, 0, 0, kvf, KVR_ + ROPE_, 0, T_, KVR_ + ROPE_, 2048);

    // 6. RoPE on q_pe (in q) and k_pe (in kvf), in place
    {
        int total_q = T_ * H_ * 32;
        rope_kernel<<<dim3((total_q + 255) / 256), 256, 0, stream>>>(
            q, cosb, sinb, H_, H_ * QKD_, QKD_, NOPE_, total_q);
        int total_k = T_ * 32;
        rope_kernel<<<dim3((total_k + 255) / 256), 256, 0, stream>>>(
            kvf, cosb, sinb, 1, KVR_ + ROPE_, 0, KVR_, total_k);
    }

    // 7. kv_n = rms(kv, kv_norm_w) in place in kvf[:, :512]
    rms_kernel<<<dim3(T_), 256, 0, stream>>>(kvf, kvf, kv_norm_w, KVR_,
                                             KVR_ + ROPE_, KVR_ + ROPE_);

    // 8. q_abs[t,h,:] = q_nope[t,h,:] @ wb1[h]   (wb1 = wkv_b_w rows h*256..+127, [128,512] K-major)
    gemm_kernel<<<dim3(KVR_ / 64, T_ / 64, H_), 256, 0, stream>>>(
        q, H_ * QKD_, QKD_,                 // A: q_nope per head (lda 3072, head stride 192)
        wkv_b_w, KVR_, (long)256 * KVR_, 1, // W: [K=128, N=512] per head
        nullptr, 0, nullptr, 0, 0,
        qabs, H_ * KVR_, KVR_, T_, KVR_, NOPE_);

    // 9. attention (q_abs -> o, same buffer)
    attn_kernel<<<dim3(S_, H_, B_), 256, 0, stream>>>(q, kvf, qabs);

    // 10. o2[t,h,:] = o[t,h,:] @ wb2[h]^T   (wb2 = rows h*256+128..+255, [128,512])
    gemm_kernel<<<dim3(VD_ / 64, T_ / 64, H_), 256, 0, stream>>>(
        qabs, H_ * KVR_, KVR_,
        wkv_b_w + (long)NOPE_ * KVR_, KVR_, (long)256 * KVR_, 0,
        nullptr, 0, nullptr, 0, 0,
        o2, H_ * VD_, VD_, T_, VD_, KVR_);

    // 11. x2 = x + o2 @ wo_w^T + wo_b
    gemm_kernel<<<dim3(D_ / 64, T_ / 64, 1), 256, 0, stream>>>(
        o2, 2048, 0, wo_w, 2048, 0, 0, wo_b, 0,
        x, 2048, 0, x2, 2048, 0, T_, D_, 2048);

    // 12. h2 = rms(x2, ffn_norm_w)
    rms_kernel<<<dim3(T_), 256, 0, stream>>>(x2, h2, ffn_nw, 2048, 2048, 2048);

    // 13. gate -> top2
    gate_kernel<<<dim3(T_), 256, 0, stream>>>(h2, gate_w, gate_b, idx, wts);

    // 14. route (counting sort by expert + tile map)
    route_kernel<<<dim3(1), 256, 0, stream>>>(idx, wts, slot_te, slot_w,
                                              tile_e, tile_row0, tile_cnt, n_tiles);

    // 15. MoE: batched per-expert GEMMs (weights read once per M-tile, not
    //     once per token). G = silu(x@W1^T+b1)*(x@W3^T+b3), then scatter
    //     y = wgt*(G@W2^T+b2) to y0/y1.
    moe_mlp13_kernel<<<dim3(MI_ / 64, MAX_TILES_), 256, 0, stream>>>(
        h2, slot_te, tile_e, tile_row0, tile_cnt, n_tiles,
        e_w1, e_b1, e_w3, e_b3, G);
    moe_mlp2_kernel<<<dim3(D_ / 64, MAX_TILES_), 256, 0, stream>>>(
        G, slot_te, slot_w, tile_e, tile_row0, tile_cnt, n_tiles,
        e_w2, e_b2, y0, y1);

    // 16. shared MLP
    gemm_kernel<<<dim3(SMI_ / 64, T_ / 64, 1), 256, 0, stream>>>(
        h2, 2048, 0, s_w1, 2048, 0, 0, s_b1, 0,
        nullptr, 0, 0, u1, SMI_, 0, T_, SMI_, 2048);
    gemm_kernel<<<dim3(SMI_ / 64, T_ / 64, 1), 256, 0, stream>>>(
        h2, 2048, 0, s_w3, 2048, 0, 0, s_b3, 0,
        nullptr, 0, 0, u3, SMI_, 0, T_, SMI_, 2048);
    {
        long n = (long)T_ * SMI_;
        silu_mul_kernel<<<dim3((unsigned)((n + 255) / 256)), 256, 0, stream>>>(u1, u3, n);
    }
    gemm_kernel<<<dim3(D_ / 64, T_ / 64, 1), 256, 0, stream>>>(
        u1, SMI_, 0, s_w2, SMI_, 0, 0, s_b2, 0,
        nullptr, 0, 0, z, D_, 0, T_, D_, SMI_);

    // 17. out = x2 + h2 + y0 + y1 + z
    {
        long n = (long)T_ * D_;
        final_add_kernel<<<dim3((unsigned)((n + 255) / 256)), 256, 0, stream>>>(
            x2, h2, y0, y1, z, (float*)d_out, n);
    }
}

// Round 2
// 5229.827 us; speedup vs baseline: 8.3466x; 2.6751x over previous
//
#include <hip/hip_runtime.h>
#include <math.h>

// Problem constants
constexpr int B_ = 2, S_ = 1024, D_ = 2048, H_ = 16;
constexpr int NOPE_ = 128, ROPE_ = 64, VD_ = 128, KVR_ = 512, QLR_ = 1536;
constexpr int NE_ = 16, MI_ = 1408, SMI_ = 2816;
constexpr int QKD_ = NOPE_ + ROPE_;            // 192
constexpr int T_ = B_ * S_;                    // 2048
constexpr float SCALE_ = 0.07216878364870322f; // 192^-0.5
constexpr float EPS_ = 1e-3f;
constexpr int MAX_TILES_ = 80;                 // sum_e ceil(n_e/64) <= 79

// ---------------------------------------------------------------------------
// Generic tiled fp32 GEMM: C[M,N] = A[M,K] @ W^T + bias + residual
// W layout: w_kn==0 -> W[N,K] row-major (ld=ldw over K)
//           w_kn==1 -> W[K,N] row-major (ld=ldw over N)   (i.e. plain A@W)
// Batched via blockIdx.z with element strides. All dims divide tile sizes
// (M%64==0, N%64==0, K%16==0 for every call below) -> no bounds checks.
// ---------------------------------------------------------------------------
__global__ __launch_bounds__(256) void gemm_kernel(
    const float* __restrict__ A, int lda, long strideA,
    const float* __restrict__ W, int ldw, long strideW, int w_kn,
    const float* __restrict__ bias, long strideBias,
    const float* __restrict__ res, int ldr, long strideRes,
    float* __restrict__ C, int ldc, long strideC,
    int M, int N, int K)
{
    (void)M;
    const int bz = blockIdx.z;
    A += (long)bz * strideA;
    W += (long)bz * strideW;
    C += (long)bz * strideC;
    if (bias) bias += (long)bz * strideBias;
    if (res)  res  += (long)bz * strideRes;

    __shared__ float As[16][68];
    __shared__ float Ws[16][68];

    const int m0 = blockIdx.y * 64;
    const int n0 = blockIdx.x * 64;
    const int tid = threadIdx.x;
    const int tx = tid & 15;   // 0..15 -> N micro
    const int ty = tid >> 4;   // 0..15 -> M micro

    float acc[4][4] = {};

    for (int kt = 0; kt < K; kt += 16) {
        #pragma unroll
        for (int i = 0; i < 4; i++) {
            int p = tid + i * 256;
            int r = p >> 4, kk = p & 15;
            As[kk][r] = A[(long)(m0 + r) * lda + (kt + kk)];
        }
        if (w_kn) {
            #pragma unroll
            for (int i = 0; i < 4; i++) {
                int p = tid + i * 256;
                int kk = p >> 6, n = p & 63;
                Ws[kk][n] = W[(long)(kt + kk) * ldw + (n0 + n)];
            }
        } else {
            #pragma unroll
            for (int i = 0; i < 4; i++) {
                int p = tid + i * 256;
                int n = p >> 4, kk = p & 15;
                Ws[kk][n] = W[(long)(n0 + n) * ldw + (kt + kk)];
            }
        }
        __syncthreads();
        #pragma unroll
        for (int kk = 0; kk < 16; kk++) {
            float a[4], b[4];
            #pragma unroll
            for (int i = 0; i < 4; i++) a[i] = As[kk][ty * 4 + i];
            #pragma unroll
            for (int j = 0; j < 4; j++) b[j] = Ws[kk][tx * 4 + j];
            #pragma unroll
            for (int i = 0; i < 4; i++)
                #pragma unroll
                for (int j = 0; j < 4; j++)
                    acc[i][j] += a[i] * b[j];
        }
        __syncthreads();
    }

    #pragma unroll
    for (int i = 0; i < 4; i++) {
        int m = m0 + ty * 4 + i;
        #pragma unroll
        for (int j = 0; j < 4; j++) {
            int n = n0 + tx * 4 + j;
            float v = acc[i][j];
            if (bias) v += bias[n];
            if (res)  v += res[(long)m * ldr + n];
            C[(long)m * ldc + n] = v;
        }
    }
}

// ---------------------------------------------------------------------------
// RMSNorm over rows: out = w * x * rsqrt(mean(x^2)+eps). In-place safe.
// ---------------------------------------------------------------------------
__global__ __launch_bounds__(256) void rms_kernel(
    const float* __restrict__ in, float* __restrict__ out,
    const float* __restrict__ w, int N, int in_stride, int out_stride)
{
    const int row = blockIdx.x;
    const float* x = in + (long)row * in_stride;
    float* y = out + (long)row * out_stride;
    __shared__ float red[256];
    const int tid = threadIdx.x;
    float s = 0.f;
    for (int i = tid; i < N; i += 256) { float v = x[i]; s += v * v; }
    red[tid] = s; __syncthreads();
    for (int st = 128; st > 0; st >>= 1) {
        if (tid < st) red[tid] += red[tid + st];
        __syncthreads();
    }
    const float scale = rsqrtf(red[0] / (float)N + EPS_);
    for (int i = tid; i < N; i += 256) y[i] = w[i] * x[i] * scale;
}

// ---------------------------------------------------------------------------
// Interleaved RoPE, in place. pos = token % S_.
// ---------------------------------------------------------------------------
__global__ void rope_kernel(float* __restrict__ p,
                            const float* __restrict__ cosb,
                            const float* __restrict__ sinb,
                            int nheads, int row_stride, int head_stride,
                            int off, int total)
{
    int i = blockIdx.x * 256 + threadIdx.x;
    if (i >= total) return;
    int pair = i & 31;
    int rem = i >> 5;
    int h = rem % nheads;
    int t = rem / nheads;
    int s = t % S_;
    float c = cosb[s * 32 + pair], sn = sinb[s * 32 + pair];
    float* base = p + (long)t * row_stride + (long)h * head_stride + off + pair * 2;
    float x0 = base[0], x1 = base[1];
    base[0] = x0 * c - x1 * sn;
    base[1] = x0 * sn + x1 * c;
}

// ---------------------------------------------------------------------------
// Row softmax over 1024-wide rows, scale folded in. One block per row.
// ---------------------------------------------------------------------------
__global__ __launch_bounds__(256) void softmax_kernel(float* __restrict__ sc)
{
    float* row = sc + (long)blockIdx.x * 1024;
    const int tid = threadIdx.x;
    __shared__ float red[256];

    float4 v = ((const float4*)row)[tid];
    v.x *= SCALE_; v.y *= SCALE_; v.z *= SCALE_; v.w *= SCALE_;

    float m = fmaxf(fmaxf(v.x, v.y), fmaxf(v.z, v.w));
    red[tid] = m; __syncthreads();
    for (int st = 128; st > 0; st >>= 1) {
        if (tid < st) red[tid] = fmaxf(red[tid], red[tid + st]);
        __syncthreads();
    }
    m = red[0];
    __syncthreads();

    v.x = __expf(v.x - m); v.y = __expf(v.y - m);
    v.z = __expf(v.z - m); v.w = __expf(v.w - m);
    float s = v.x + v.y + v.z + v.w;
    red[tid] = s; __syncthreads();
    for (int st = 128; st > 0; st >>= 1) {
        if (tid < st) red[tid] += red[tid + st];
        __syncthreads();
    }
    const float inv = 1.f / red[0];

    v.x *= inv; v.y *= inv; v.z *= inv; v.w *= inv;
    ((float4*)row)[tid] = v;
}

// ---------------------------------------------------------------------------
// Gate: logits -> softmax -> top2 on (probs + gate_b), weights = probs[idx]
// ---------------------------------------------------------------------------
__global__ __launch_bounds__(256) void gate_kernel(
    const float* __restrict__ h2, const float* __restrict__ gw,
    const float* __restrict__ gb, int* __restrict__ idx,
    float* __restrict__ wts)
{
    const int t = blockIdx.x;
    __shared__ float red[256];
    __shared__ float logits[16];
    const int tid = threadIdx.x;
    const int e = tid >> 4, lane = tid & 15;
    const float* x = h2 + (long)t * 2048;
    float s = 0.f;
    for (int i = lane; i < 2048; i += 16) s += x[i] * gw[e * 2048 + i];
    red[tid] = s; __syncthreads();
    for (int st = 8; st > 0; st >>= 1) {
        if (lane < st) red[tid] += red[tid + st];
        __syncthreads();
    }
    if (lane == 0) logits[e] = red[e * 16] + gb[e];
    __syncthreads();
    if (tid == 0) {
        float m = logits[0];
        for (int j = 1; j < 16; j++) m = fmaxf(m, logits[j]);
        float pr[16]; float sum = 0.f;
        for (int j = 0; j < 16; j++) { pr[j] = expf(logits[j] - m); sum += pr[j]; }
        float inv = 1.f / sum;
        for (int j = 0; j < 16; j++) pr[j] *= inv;
        int i1 = 0; float v1 = -1e30f;
        for (int j = 0; j < 16; j++) { float v = pr[j] + gb[j]; if (v > v1) { v1 = v; i1 = j; } }
        int i2 = 0; float v2 = -1e30f;
        for (int j = 0; j < 16; j++) { if (j == i1) continue; float v = pr[j] + gb[j]; if (v > v2) { v2 = v; i2 = j; } }
        idx[t * 2 + 0] = i1; idx[t * 2 + 1] = i2;
        wts[t * 2 + 0] = pr[i1]; wts[t * 2 + 1] = pr[i2];
    }
}

// ---------------------------------------------------------------------------
// Route: sort the 2T (token, k) assignments by expert (counting sort) and
// emit a tile map: tiles of up to 64 consecutive slots of the same expert.
// slot_te[pos*2] = (t<<1)|k ; slot_te[pos*2+1] = e ; slot_w[pos] = weight
// ---------------------------------------------------------------------------
__global__ __launch_bounds__(256) void route_kernel(
    const int* __restrict__ idx, const float* __restrict__ wts,
    int* __restrict__ slot_te, float* __restrict__ slot_w,
    int* __restrict__ tile_e, int* __restrict__ tile_row0,
    int* __restrict__ tile_cnt, int* __restrict__ n_tiles)
{
    __shared__ int counts[16], offs[16], cursor[16];
    const int tid = threadIdx.x;
    if (tid < 16) { counts[tid] = 0; cursor[tid] = 0; }
    __syncthreads();
    for (int a = tid; a < 2 * T_; a += 256) atomicAdd(&counts[idx[a]], 1);
    __syncthreads();
    if (tid == 0) {
        int o = 0;
        for (int e = 0; e < 16; e++) { offs[e] = o; o += counts[e]; }
        // tile map
        int nt = 0;
        for (int e = 0; e < 16; e++) {
            for (int r0 = 0; r0 < counts[e]; r0 += 64) {
                tile_e[nt] = e;
                tile_row0[nt] = offs[e] + r0;
                int c = counts[e] - r0;
                tile_cnt[nt] = c < 64 ? c : 64;
                nt++;
            }
        }
        *n_tiles = nt;
    }
    __syncthreads();
    for (int a = tid; a < 2 * T_; a += 256) {
        int e = idx[a];
        int pos = offs[e] + atomicAdd(&cursor[e], 1);
        int t = a >> 1, k = a & 1;
        slot_te[pos * 2 + 0] = (t << 1) | k;
        slot_te[pos * 2 + 1] = e;
        slot_w[pos] = wts[a];
    }
}

// ---------------------------------------------------------------------------
// MoE stage 1: batched per-expert GEMM. One block = 64 slots x 64 mi-cols.
// G[slot, i] = silu(x@W1^T + b1) * (x@W3^T + b3), x gathered from h2 by the
// routed token index. Grid: (MI/64, MAX_TILES); tiles >= n_tiles exit.
// ---------------------------------------------------------------------------
__global__ __launch_bounds__(256) void moe_mlp13_kernel(
    const float* __restrict__ h2,
    const int* __restrict__ slot_te,
    const int* __restrict__ tile_e, const int* __restrict__ tile_row0,
    const int* __restrict__ tile_cnt, const int* __restrict__ n_tiles,
    const float* __restrict__ w1, const float* __restrict__ b1,
    const float* __restrict__ w3, const float* __restrict__ b3,
    float* __restrict__ G)
{
    const int tile = blockIdx.y;
    if (tile >= *n_tiles) return;
    const int e    = tile_e[tile];
    const int row0 = tile_row0[tile];
    const int tcnt = tile_cnt[tile];
    const int n0   = blockIdx.x * 64;

    __shared__ float As[16][68];
    __shared__ float W1s[16][68];
    __shared__ float W3s[16][68];
    __shared__ int tok[64];

    const int tid = threadIdx.x;
    if (tid < 64) {
        int r = tid < tcnt ? tid : tcnt - 1;        // clamp padded rows
        tok[tid] = slot_te[(row0 + r) * 2 + 0] >> 1;
    }
    __syncthreads();

    const float* W1 = w1 + (long)e * MI_ * 2048;
    const float* W3 = w3 + (long)e * MI_ * 2048;

    const int tx = tid & 15, ty = tid >> 4;
    float acc1[4][4] = {}, acc3[4][4] = {};

    for (int kt = 0; kt < 2048; kt += 16) {
        #pragma unroll
        for (int i = 0; i < 4; i++) {
            int p = tid + i * 256;
            int r = p >> 4, kk = p & 15;
            As[kk][r] = h2[(long)tok[r] * 2048 + (kt + kk)];
        }
        #pragma unroll
        for (int i = 0; i < 4; i++) {
            int p = tid + i * 256;
            int n = p >> 4, kk = p & 15;
            W1s[kk][n] = W1[(long)(n0 + n) * 2048 + (kt + kk)];
            W3s[kk][n] = W3[(long)(n0 + n) * 2048 + (kt + kk)];
        }
        __syncthreads();
        #pragma unroll
        for (int kk = 0; kk < 16; kk++) {
            float a[4], b[4], c[4];
            #pragma unroll
            for (int i = 0; i < 4; i++) a[i] = As[kk][ty * 4 + i];
            #pragma unroll
            for (int j = 0; j < 4; j++) {
                b[j] = W1s[kk][tx * 4 + j];
                c[j] = W3s[kk][tx * 4 + j];
            }
            #pragma unroll
            for (int i = 0; i < 4; i++)
                #pragma unroll
                for (int j = 0; j < 4; j++) {
                    acc1[i][j] += a[i] * b[j];
                    acc3[i][j] += a[i] * c[j];
                }
        }
        __syncthreads();
    }

    #pragma unroll
    for (int i = 0; i < 4; i++) {
        int rl = ty * 4 + i;
        if (rl >= tcnt) continue;
        long grow = (long)(row0 + rl) * MI_;
        #pragma unroll
        for (int j = 0; j < 4; j++) {
            int n = n0 + tx * 4 + j;
            float a = acc1[i][j] + b1[e * MI_ + n];
            float b = acc3[i][j] + b3[e * MI_ + n];
            G[grow + n] = (a / (1.f + expf(-a))) * b;
        }
    }
}

// ---------------------------------------------------------------------------
// MoE stage 2: Y[slot, d] = wgt * (G[slot] @ W2[e]^T + b2[e]), scattered to
// y0/y1 by (t, k). Grid: (D/64, MAX_TILES).
// ---------------------------------------------------------------------------
__global__ __launch_bounds__(256) void moe_mlp2_kernel(
    const float* __restrict__ G,
    const int* __restrict__ slot_te, const float* __restrict__ slot_w,
    const int* __restrict__ tile_e, const int* __restrict__ tile_row0,
    const int* __restrict__ tile_cnt, const int* __restrict__ n_tiles,
    const float* __restrict__ w2, const float* __restrict__ b2,
    float* __restrict__ y0, float* __restrict__ y1)
{
    const int tile = blockIdx.y;
    if (tile >= *n_tiles) return;
    const int e    = tile_e[tile];
    const int row0 = tile_row0[tile];
    const int tcnt = tile_cnt[tile];
    const int n0   = blockIdx.x * 64;

    __shared__ float As[16][68];
    __shared__ float Ws[16][68];
    __shared__ int rsrc[64];

    const int tid = threadIdx.x;
    if (tid < 64) {
        int r = tid < tcnt ? tid : tcnt - 1;
        rsrc[tid] = row0 + r;
    }
    __syncthreads();

    const float* W2 = w2 + (long)e * 2048 * MI_;

    const int tx = tid & 15, ty = tid >> 4;
    float acc[4][4] = {};

    for (int kt = 0; kt < MI_; kt += 16) {
        #pragma unroll
        for (int i = 0; i < 4; i++) {
            int p = tid + i * 256;
            int r = p >> 4, kk = p & 15;
            As[kk][r] = G[(long)rsrc[r] * MI_ + (kt + kk)];
        }
        #pragma unroll
        for (int i = 0; i < 4; i++) {
            int p = tid + i * 256;
            int n = p >> 4, kk = p & 15;
            Ws[kk][n] = W2[(long)(n0 + n) * MI_ + (kt + kk)];
        }
        __syncthreads();
        #pragma unroll
        for (int kk = 0; kk < 16; kk++) {
            float a[4], b[4];
            #pragma unroll
            for (int i = 0; i < 4; i++) a[i] = As[kk][ty * 4 + i];
            #pragma unroll
            for (int j = 0; j < 4; j++) b[j] = Ws[kk][tx * 4 + j];
            #pragma unroll
            for (int i = 0; i < 4; i++)
                #pragma unroll
                for (int j = 0; j < 4; j++)
                    acc[i][j] += a[i] * b[j];
        }
        __syncthreads();
    }

    #pragma unroll
    for (int i = 0; i < 4; i++) {
        int rl = ty * 4 + i;
        if (rl >= tcnt) continue;
        int slot = row0 + rl;
        int tk = slot_te[slot * 2 + 0];
        int t = tk >> 1, k = tk & 1;
        float wgt = slot_w[slot];
        float* y = (k ? y1 : y0) + (long)t * 2048;
        #pragma unroll
        for (int j = 0; j < 4; j++) {
            int n = n0 + tx * 4 + j;
            y[n] = wgt * (acc[i][j] + b2[e * 2048 + n]);
        }
    }
}

// ---------------------------------------------------------------------------
// u1 = silu(u1) * u3
// ---------------------------------------------------------------------------
__global__ void silu_mul_kernel(float* __restrict__ u1,
                                const float* __restrict__ u3, long n)
{
    long i = (long)blockIdx.x * 256 + threadIdx.x;
    if (i >= n) return;
    float a = u1[i];
    u1[i] = (a / (1.f + expf(-a))) * u3[i];
}

// ---------------------------------------------------------------------------
// out = x2 + h2 + y0 + y1 + z
// ---------------------------------------------------------------------------
__global__ void final_add_kernel(const float* __restrict__ x2,
                                 const float* __restrict__ h2,
                                 const float* __restrict__ y0,
                                 const float* __restrict__ y1,
                                 const float* __restrict__ z,
                                 float* __restrict__ out, long n)
{
    long i = (long)blockIdx.x * 256 + threadIdx.x;
    if (i >= n) return;
    out[i] = x2[i] + h2[i] + y0[i] + y1[i] + z[i];
}

// ---------------------------------------------------------------------------
extern "C" void kernel_launch(void* const* d_in, const int* in_sizes, int n_in,
                              void* d_out, int out_size, void* d_ws, size_t ws_size,
                              hipStream_t stream)
{
    (void)in_sizes; (void)n_in; (void)out_size; (void)ws_size;

    const float* x          = (const float*)d_in[0];
    const float* attn_nw    = (const float*)d_in[1];
    const float* ffn_nw     = (const float*)d_in[2];
    const float* wq_a_w     = (const float*)d_in[3];
    const float* wq_a_b     = (const float*)d_in[4];
    const float* q_norm_w   = (const float*)d_in[5];
    const float* wq_b_w     = (const float*)d_in[6];
    const float* wq_b_b     = (const float*)d_in[7];
    const float* wkv_a_w    = (const float*)d_in[8];
    const float* wkv_a_b    = (const float*)d_in[9];
    const float* kv_norm_w  = (const float*)d_in[10];
    const float* wkv_b_w    = (const float*)d_in[11];
    const float* wo_w       = (const float*)d_in[12];
    const float* wo_b       = (const float*)d_in[13];
    const float* gate_w     = (const float*)d_in[14];
    const float* gate_b     = (const float*)d_in[15];
    const float* e_w1       = (const float*)d_in[16];
    const float* e_b1       = (const float*)d_in[17];
    const float* e_w2       = (const float*)d_in[18];
    const float* e_b2       = (const float*)d_in[19];
    const float* e_w3       = (const float*)d_in[20];
    const float* e_b3       = (const float*)d_in[21];
    const float* s_w1       = (const float*)d_in[22];
    const float* s_b1       = (const float*)d_in[23];
    const float* s_w2       = (const float*)d_in[24];
    const float* s_b2       = (const float*)d_in[25];
    const float* s_w3       = (const float*)d_in[26];
    const float* s_b3       = (const float*)d_in[27];
    const float* cosb       = (const float*)d_in[28];
    const float* sinb       = (const float*)d_in[29];

    float* ws = (float*)d_ws;
    // Workspace layout (floats)
    float* h    = ws + 0;            // T*2048          (reused later as y0)
    float* qa   = ws + 4194304;      // T*1536
    float* q    = ws + 7340032;      // T*3072          (reused later as y1)
    float* kvf  = ws + 13631488;     // T*576
    float* qabs = ws + 14811136;     // T*H*512 = 16.8M (q_abs, then o, then G)
    float* o2   = ws + 31588352;     // T*2048
    float* x2   = ws + 35782656;     // T*2048
    float* h2   = ws + 39976960;     // T*2048
    float* u1   = ws + 44171264;     // T*2816
    float* u3   = ws + 49938432;     // T*2816          (reused later as z)
    float* wts  = ws + 55705600;     // T*2 floats
    int*   idx  = (int*)(ws + 55709696);     // T*2 ints
    int*   slot_te = (int*)(ws + 55713792);  // 2T*2 ints
    float* slot_w  = ws + 55721984;          // 2T floats
    float* y0 = h;
    float* y1 = q;
    float* z  = u3;

    // Attention scores scratch: [H][S][S] per batch = 16.8M floats, living in
    // the o2/x2/h2/u1 region (all dead until step 10).
    float* scores = o2;

    // MoE scratch inside the (dead after step 10) qabs region:
    float* G = qabs;                              // 2T * MI = 5,767,168 floats
    int* tile_e    = (int*)(qabs + 5767168);      // MAX_TILES
    int* tile_row0 = tile_e + MAX_TILES_;
    int* tile_cnt  = tile_e + 2 * MAX_TILES_;
    int* n_tiles   = tile_e + 3 * MAX_TILES_;

    // 1. h = rms(x, attn_norm_w)
    rms_kernel<<<dim3(T_), 256, 0, stream>>>(x, h, attn_nw, 2048, 2048, 2048);

    // 2. qa = h @ wq_a_w^T + wq_a_b            [T,1536]
    gemm_kernel<<<dim3(QLR_ / 64, T_ / 64, 1), 256, 0, stream>>>(
        h, 2048, 0, wq_a_w, 2048, 0, 0, wq_a_b, 0,
        nullptr, 0, 0, qa, QLR_, 0, T_, QLR_, 2048);

    // 3. qa = rms(qa, q_norm_w) in place
    rms_kernel<<<dim3(T_), 256, 0, stream>>>(qa, qa, q_norm_w, QLR_, QLR_, QLR_);

    // 4. q = qa @ wq_b_w^T + wq_b_b            [T, 3072]
    gemm_kernel<<<dim3(H_ * QKD_ / 64, T_ / 64, 1), 256, 0, stream>>>(
        qa, QLR_, 0, wq_b_w, QLR_, 0, 0, wq_b_b, 0,
        nullptr, 0, 0, q, H_ * QKD_, 0, T_, H_ * QKD_, QLR_);

    // 5. kvf = h @ wkv_a_w^T + wkv_a_b         [T, 576]
    gemm_kernel<<<dim3((KVR_ + ROPE_) / 64, T_ / 64, 1), 256, 0, stream>>>(
        h, 2048, 0, wkv_a_w, 2048, 0, 0, wkv_a_b, 0,
        nullptr, 0, 0, kvf, KVR_ + ROPE_, 0, T_, KVR_ + ROPE_, 2048);

    // 6. RoPE on q_pe (in q) and k_pe (in kvf), in place
    {
        int total_q = T_ * H_ * 32;
        rope_kernel<<<dim3((total_q + 255) / 256), 256, 0, stream>>>(
            q, cosb, sinb, H_, H_ * QKD_, QKD_, NOPE_, total_q);
        int total_k = T_ * 32;
        rope_kernel<<<dim3((total_k + 255) / 256), 256, 0, stream>>>(
            kvf, cosb, sinb, 1, KVR_ + ROPE_, 0, KVR_, total_k);
    }

    // 7. kv_n = rms(kv, kv_norm_w) in place in kvf[:, :512]
    rms_kernel<<<dim3(T_), 256, 0, stream>>>(kvf, kvf, kv_norm_w, KVR_,
                                             KVR_ + ROPE_, KVR_ + ROPE_);

    // 8. q_abs[t,h,:] = q_nope[t,h,:] @ wb1[h]   (wb1 = wkv_b_w rows h*256..+127, [128,512] K-major)
    gemm_kernel<<<dim3(KVR_ / 64, T_ / 64, H_), 256, 0, stream>>>(
        q, H_ * QKD_, QKD_,                 // A: q_nope per head (lda 3072, head stride 192)
        wkv_b_w, KVR_, (long)256 * KVR_, 1, // W: [K=128, N=512] per head
        nullptr, 0, nullptr, 0, 0,
        qabs, H_ * KVR_, KVR_, T_, KVR_, NOPE_);

    // 9. attention as batched GEMMs per batch b (scores in dead o2/x2/h2/u1
    //    region). scores[h,s,t] -> softmax -> o back into qabs.
    for (int b = 0; b < B_; b++) {
        const float* kvb = kvf + (long)b * S_ * (KVR_ + ROPE_);
        // 9a. scores = q_abs . kv_n^T       (M=S, N=S, K=512, z=heads)
        gemm_kernel<<<dim3(S_ / 64, S_ / 64, H_), 256, 0, stream>>>(
            qabs + (long)b * S_ * H_ * KVR_, H_ * KVR_, KVR_,
            kvb, KVR_ + ROPE_, 0, 0,
            nullptr, 0, nullptr, 0, 0,
            scores, S_, (long)S_ * S_, S_, S_, KVR_);
        // 9b. scores += q_pe . k_pe^T       (K=64, res-accumulate)
        gemm_kernel<<<dim3(S_ / 64, S_ / 64, H_), 256, 0, stream>>>(
            q + (long)b * S_ * H_ * QKD_ + NOPE_, H_ * QKD_, QKD_,
            kvb + KVR_, KVR_ + ROPE_, 0, 0,
            nullptr, 0, scores, S_, (long)S_ * S_,
            scores, S_, (long)S_ * S_, S_, S_, ROPE_);
        // 9c. softmax rows (SCALE folded in)
        softmax_kernel<<<dim3(H_ * S_), 256, 0, stream>>>(scores);
        // 9d. o = P @ kv_n                  (M=S, N=512, K=S)
        gemm_kernel<<<dim3(KVR_ / 64, S_ / 64, H_), 256, 0, stream>>>(
            scores, S_, (long)S_ * S_,
            kvb, KVR_ + ROPE_, 0, 1,
            nullptr, 0, nullptr, 0, 0,
            qabs + (long)b * S_ * H_ * KVR_, H_ * KVR_, KVR_, S_, KVR_, S_);
    }

    // 10. o2[t,h,:] = o[t,h,:] @ wb2[h]^T   (wb2 = rows h*256+128..+255, [128,512])
    gemm_kernel<<<dim3(VD_ / 64, T_ / 64, H_), 256, 0, stream>>>(
        qabs, H_ * KVR_, KVR_,
        wkv_b_w + (long)NOPE_ * KVR_, KVR_, (long)256 * KVR_, 0,
        nullptr, 0, nullptr, 0, 0,
        o2, H_ * VD_, VD_, T_, VD_, KVR_);

    // 11. x2 = x + o2 @ wo_w^T + wo_b
    gemm_kernel<<<dim3(D_ / 64, T_ / 64, 1), 256, 0, stream>>>(
        o2, 2048, 0, wo_w, 2048, 0, 0, wo_b, 0,
        x, 2048, 0, x2, 2048, 0, T_, D_, 2048);

    // 12. h2 = rms(x2, ffn_norm_w)
    rms_kernel<<<dim3(T_), 256, 0, stream>>>(x2, h2, ffn_nw, 2048, 2048, 2048);

    // 13. gate -> top2
    gate_kernel<<<dim3(T_), 256, 0, stream>>>(h2, gate_w, gate_b, idx, wts);

    // 14. route (counting sort by expert + tile map)
    route_kernel<<<dim3(1), 256, 0, stream>>>(idx, wts, slot_te, slot_w,
                                              tile_e, tile_row0, tile_cnt, n_tiles);

    // 15. MoE: batched per-expert GEMMs (weights read once per M-tile, not
    //     once per token). G = silu(x@W1^T+b1)*(x@W3^T+b3), then scatter
    //     y = wgt*(G@W2^T+b2) to y0/y1.
    moe_mlp13_kernel<<<dim3(MI_ / 64, MAX_TILES_), 256, 0, stream>>>(
        h2, slot_te, tile_e, tile_row0, tile_cnt, n_tiles,
        e_w1, e_b1, e_w3, e_b3, G);
    moe_mlp2_kernel<<<dim3(D_ / 64, MAX_TILES_), 256, 0, stream>>>(
        G, slot_te, slot_w, tile_e, tile_row0, tile_cnt, n_tiles,
        e_w2, e_b2, y0, y1);

    // 16. shared MLP
    gemm_kernel<<<dim3(SMI_ / 64, T_ / 64, 1), 256, 0, stream>>>(
        h2, 2048, 0, s_w1, 2048, 0, 0, s_b1, 0,
        nullptr, 0, 0, u1, SMI_, 0, T_, SMI_, 2048);
    gemm_kernel<<<dim3(SMI_ / 64, T_ / 64, 1), 256, 0, stream>>>(
        h2, 2048, 0, s_w3, 2048, 0, 0, s_b3, 0,
        nullptr, 0, 0, u3, SMI_, 0, T_, SMI_, 2048);
    {
        long n = (long)T_ * SMI_;
        silu_mul_kernel<<<dim3((unsigned)((n + 255) / 256)), 256, 0, stream>>>(u1, u3, n);
    }
    gemm_kernel<<<dim3(D_ / 64, T_ / 64, 1), 256, 0, stream>>>(
        u1, SMI_, 0, s_w2, SMI_, 0, 0, s_b2, 0,
        nullptr, 0, 0, z, D_, 0, T_, D_, SMI_);

    // 17. out = x2 + h2 + y0 + y1 + z
    {
        long n = (long)T_ * D_;
        final_add_kernel<<<dim3((unsigned)((n + 255) / 256)), 256, 0, stream>>>(
            x2, h2, y0, y1, z, (float*)d_out, n);
    }
}

// Round 3
// 2740.088 us; speedup vs baseline: 15.9307x; 1.9086x over previous
//
#include <hip/hip_runtime.h>
#include <math.h>

// Problem constants
constexpr int B_ = 2, S_ = 1024, D_ = 2048, H_ = 16;
constexpr int NOPE_ = 128, ROPE_ = 64, VD_ = 128, KVR_ = 512, QLR_ = 1536;
constexpr int NE_ = 16, MI_ = 1408, SMI_ = 2816;
constexpr int QKD_ = NOPE_ + ROPE_;            // 192
constexpr int T_ = B_ * S_;                    // 2048
constexpr float SCALE_ = 0.07216878364870322f; // 192^-0.5
constexpr float EPS_ = 1e-3f;
constexpr int MAX_TILES_ = 80;                 // sum_e ceil(n_e/64) <= 79

typedef __attribute__((ext_vector_type(8))) short  bf16x8_t;
typedef __attribute__((ext_vector_type(4))) float  f32x4_t;
typedef __attribute__((ext_vector_type(4))) unsigned short us4_t;

// Split fp32 into bf16 hi + bf16 lo (round-to-nearest-even both).
__device__ __forceinline__ void split_bf(float v, unsigned short& h, unsigned short& l)
{
    unsigned int u = __float_as_uint(v);
    unsigned short hb = (unsigned short)((u + 0x7FFFu + ((u >> 16) & 1u)) >> 16);
    float hf = __uint_as_float((unsigned int)hb << 16);
    float lo = v - hf;
    unsigned int u2 = __float_as_uint(lo);
    l = (unsigned short)((u2 + 0x7FFFu + ((u2 >> 16) & 1u)) >> 16);
    h = hb;
}

// ---------------------------------------------------------------------------
// MFMA bf16x3 GEMM: C[M,N] = A[M,K] @ W^T + bias + res. 128x128 tile, BK=32.
// 4 waves (2x2), each wave 64x64 (4x4 of 16x16x32 MFMA), fp32 accumulate.
// Precision: hi*hi + hi*lo + lo*hi  (~fp32). Requires M%128==0, N%128==0,
// K%32==0. w_kn as in gemm_kernel (0: W[N,K], 1: W[K,N] -> LDS transpose).
// ---------------------------------------------------------------------------
__global__ __launch_bounds__(256) void gemm_mfma_kernel(
    const float* __restrict__ A, int lda, long strideA,
    const float* __restrict__ W, int ldw, long strideW, int w_kn,
    const float* __restrict__ bias, long strideBias,
    const float* __restrict__ res, int ldr, long strideRes,
    float* __restrict__ C, int ldc, long strideC,
    int M, int N, int K)
{
    (void)M; (void)N;
    const int bz = blockIdx.z;
    A += (long)bz * strideA;
    W += (long)bz * strideW;
    C += (long)bz * strideC;
    if (bias) bias += (long)bz * strideBias;
    if (res)  res  += (long)bz * strideRes;

    __shared__ unsigned short Ah[128][40], Al[128][40];
    __shared__ unsigned short Bh[128][40], Bl[128][40];

    const int m0 = blockIdx.y * 128;
    const int n0 = blockIdx.x * 128;
    const int tid  = threadIdx.x;
    const int lane = tid & 63;
    const int wv   = tid >> 6;
    const int wm = (wv >> 1) * 64, wn = (wv & 1) * 64;
    const int r16 = lane & 15, g4 = lane >> 4;

    f32x4_t acc[4][4];
    #pragma unroll
    for (int i = 0; i < 4; i++)
        #pragma unroll
        for (int j = 0; j < 4; j++) acc[i][j] = (f32x4_t){0.f, 0.f, 0.f, 0.f};

    const int sr   = tid >> 3;        // 0..31
    const int scol = (tid & 7) * 4;   // 0,4,..,28
    const int tcol = tid & 63, tkr = tid >> 6;

    for (int kt = 0; kt < K; kt += 32) {
        // ---- stage A[128][32] as bf16 hi/lo ----
        #pragma unroll
        for (int rr = 0; rr < 128; rr += 32) {
            const float4 v = *(const float4*)(A + (long)(m0 + rr + sr) * lda + (kt + scol));
            us4_t h, l;
            split_bf(v.x, ((unsigned short*)&h)[0], ((unsigned short*)&l)[0]);
            split_bf(v.y, ((unsigned short*)&h)[1], ((unsigned short*)&l)[1]);
            split_bf(v.z, ((unsigned short*)&h)[2], ((unsigned short*)&l)[2]);
            split_bf(v.w, ((unsigned short*)&h)[3], ((unsigned short*)&l)[3]);
            *(us4_t*)&Ah[rr + sr][scol] = h;
            *(us4_t*)&Al[rr + sr][scol] = l;
        }
        // ---- stage W tile as [n][k] bf16 hi/lo ----
        if (w_kn == 0) {
            #pragma unroll
            for (int rr = 0; rr < 128; rr += 32) {
                const float4 v = *(const float4*)(W + (long)(n0 + rr + sr) * ldw + (kt + scol));
                us4_t h, l;
                split_bf(v.x, ((unsigned short*)&h)[0], ((unsigned short*)&l)[0]);
                split_bf(v.y, ((unsigned short*)&h)[1], ((unsigned short*)&l)[1]);
                split_bf(v.z, ((unsigned short*)&h)[2], ((unsigned short*)&l)[2]);
                split_bf(v.w, ((unsigned short*)&h)[3], ((unsigned short*)&l)[3]);
                *(us4_t*)&Bh[rr + sr][scol] = h;
                *(us4_t*)&Bl[rr + sr][scol] = l;
            }
        } else {
            #pragma unroll
            for (int cb = 0; cb < 128; cb += 64)
                #pragma unroll
                for (int kb = 0; kb < 32; kb += 4) {
                    float v = W[(long)(kt + kb + tkr) * ldw + (n0 + cb + tcol)];
                    unsigned short h, l;
                    split_bf(v, h, l);
                    Bh[cb + tcol][kb + tkr] = h;
                    Bl[cb + tcol][kb + tkr] = l;
                }
        }
        __syncthreads();

        bf16x8_t ah[4], al[4], bh[4], bl[4];
        #pragma unroll
        for (int i = 0; i < 4; i++) {
            ah[i] = *(const bf16x8_t*)&Ah[wm + i * 16 + r16][g4 * 8];
            al[i] = *(const bf16x8_t*)&Al[wm + i * 16 + r16][g4 * 8];
            bh[i] = *(const bf16x8_t*)&Bh[wn + i * 16 + r16][g4 * 8];
            bl[i] = *(const bf16x8_t*)&Bl[wn + i * 16 + r16][g4 * 8];
        }
        #pragma unroll
        for (int i = 0; i < 4; i++)
            #pragma unroll
            for (int j = 0; j < 4; j++) {
                f32x4_t t = acc[i][j];
                t = __builtin_amdgcn_mfma_f32_16x16x32_bf16(ah[i], bh[j], t, 0, 0, 0);
                t = __builtin_amdgcn_mfma_f32_16x16x32_bf16(ah[i], bl[j], t, 0, 0, 0);
                t = __builtin_amdgcn_mfma_f32_16x16x32_bf16(al[i], bh[j], t, 0, 0, 0);
                acc[i][j] = t;
            }
        __syncthreads();
    }

    #pragma unroll
    for (int i = 0; i < 4; i++)
        #pragma unroll
        for (int rr = 0; rr < 4; rr++) {
            const int m = m0 + wm + i * 16 + g4 * 4 + rr;
            #pragma unroll
            for (int j = 0; j < 4; j++) {
                const int n = n0 + wn + j * 16 + r16;
                float v = acc[i][j][rr];
                if (bias) v += bias[n];
                if (res)  v += res[(long)m * ldr + n];
                C[(long)m * ldc + n] = v;
            }
        }
}

// ---------------------------------------------------------------------------
// Legacy fp32 tiled GEMM (kept only for N%128!=0 call sites, i.e. step 5).
// ---------------------------------------------------------------------------
__global__ __launch_bounds__(256) void gemm_kernel(
    const float* __restrict__ A, int lda, long strideA,
    const float* __restrict__ W, int ldw, long strideW, int w_kn,
    const float* __restrict__ bias, long strideBias,
    const float* __restrict__ res, int ldr, long strideRes,
    float* __restrict__ C, int ldc, long strideC,
    int M, int N, int K)
{
    (void)M;
    const int bz = blockIdx.z;
    A += (long)bz * strideA;
    W += (long)bz * strideW;
    C += (long)bz * strideC;
    if (bias) bias += (long)bz * strideBias;
    if (res)  res  += (long)bz * strideRes;

    __shared__ float As[16][68];
    __shared__ float Ws[16][68];

    const int m0 = blockIdx.y * 64;
    const int n0 = blockIdx.x * 64;
    const int tid = threadIdx.x;
    const int tx = tid & 15;
    const int ty = tid >> 4;

    float acc[4][4] = {};

    for (int kt = 0; kt < K; kt += 16) {
        #pragma unroll
        for (int i = 0; i < 4; i++) {
            int p = tid + i * 256;
            int r = p >> 4, kk = p & 15;
            As[kk][r] = A[(long)(m0 + r) * lda + (kt + kk)];
        }
        if (w_kn) {
            #pragma unroll
            for (int i = 0; i < 4; i++) {
                int p = tid + i * 256;
                int kk = p >> 6, n = p & 63;
                Ws[kk][n] = W[(long)(kt + kk) * ldw + (n0 + n)];
            }
        } else {
            #pragma unroll
            for (int i = 0; i < 4; i++) {
                int p = tid + i * 256;
                int n = p >> 4, kk = p & 15;
                Ws[kk][n] = W[(long)(n0 + n) * ldw + (kt + kk)];
            }
        }
        __syncthreads();
        #pragma unroll
        for (int kk = 0; kk < 16; kk++) {
            float a[4], b[4];
            #pragma unroll
            for (int i = 0; i < 4; i++) a[i] = As[kk][ty * 4 + i];
            #pragma unroll
            for (int j = 0; j < 4; j++) b[j] = Ws[kk][tx * 4 + j];
            #pragma unroll
            for (int i = 0; i < 4; i++)
                #pragma unroll
                for (int j = 0; j < 4; j++)
                    acc[i][j] += a[i] * b[j];
        }
        __syncthreads();
    }

    #pragma unroll
    for (int i = 0; i < 4; i++) {
        int m = m0 + ty * 4 + i;
        #pragma unroll
        for (int j = 0; j < 4; j++) {
            int n = n0 + tx * 4 + j;
            float v = acc[i][j];
            if (bias) v += bias[n];
            if (res)  v += res[(long)m * ldr + n];
            C[(long)m * ldc + n] = v;
        }
    }
}

// ---------------------------------------------------------------------------
// RMSNorm over rows.
// ---------------------------------------------------------------------------
__global__ __launch_bounds__(256) void rms_kernel(
    const float* __restrict__ in, float* __restrict__ out,
    const float* __restrict__ w, int N, int in_stride, int out_stride)
{
    const int row = blockIdx.x;
    const float* x = in + (long)row * in_stride;
    float* y = out + (long)row * out_stride;
    __shared__ float red[256];
    const int tid = threadIdx.x;
    float s = 0.f;
    for (int i = tid; i < N; i += 256) { float v = x[i]; s += v * v; }
    red[tid] = s; __syncthreads();
    for (int st = 128; st > 0; st >>= 1) {
        if (tid < st) red[tid] += red[tid + st];
        __syncthreads();
    }
    const float scale = rsqrtf(red[0] / (float)N + EPS_);
    for (int i = tid; i < N; i += 256) y[i] = w[i] * x[i] * scale;
}

// ---------------------------------------------------------------------------
// Interleaved RoPE, in place.
// ---------------------------------------------------------------------------
__global__ void rope_kernel(float* __restrict__ p,
                            const float* __restrict__ cosb,
                            const float* __restrict__ sinb,
                            int nheads, int row_stride, int head_stride,
                            int off, int total)
{
    int i = blockIdx.x * 256 + threadIdx.x;
    if (i >= total) return;
    int pair = i & 31;
    int rem = i >> 5;
    int h = rem % nheads;
    int t = rem / nheads;
    int s = t % S_;
    float c = cosb[s * 32 + pair], sn = sinb[s * 32 + pair];
    float* base = p + (long)t * row_stride + (long)h * head_stride + off + pair * 2;
    float x0 = base[0], x1 = base[1];
    base[0] = x0 * c - x1 * sn;
    base[1] = x0 * sn + x1 * c;
}

// ---------------------------------------------------------------------------
// Row softmax over 1024-wide rows, scale folded in.
// ---------------------------------------------------------------------------
__global__ __launch_bounds__(256) void softmax_kernel(float* __restrict__ sc)
{
    float* row = sc + (long)blockIdx.x * 1024;
    const int tid = threadIdx.x;
    __shared__ float red[256];

    float4 v = ((const float4*)row)[tid];
    v.x *= SCALE_; v.y *= SCALE_; v.z *= SCALE_; v.w *= SCALE_;

    float m = fmaxf(fmaxf(v.x, v.y), fmaxf(v.z, v.w));
    red[tid] = m; __syncthreads();
    for (int st = 128; st > 0; st >>= 1) {
        if (tid < st) red[tid] = fmaxf(red[tid], red[tid + st]);
        __syncthreads();
    }
    m = red[0];
    __syncthreads();

    v.x = __expf(v.x - m); v.y = __expf(v.y - m);
    v.z = __expf(v.z - m); v.w = __expf(v.w - m);
    float s = v.x + v.y + v.z + v.w;
    red[tid] = s; __syncthreads();
    for (int st = 128; st > 0; st >>= 1) {
        if (tid < st) red[tid] += red[tid + st];
        __syncthreads();
    }
    const float inv = 1.f / red[0];

    v.x *= inv; v.y *= inv; v.z *= inv; v.w *= inv;
    ((float4*)row)[tid] = v;
}

// ---------------------------------------------------------------------------
// Gate: logits -> softmax -> top2 on (probs + gate_b), weights = probs[idx]
// ---------------------------------------------------------------------------
__global__ __launch_bounds__(256) void gate_kernel(
    const float* __restrict__ h2, const float* __restrict__ gw,
    const float* __restrict__ gb, int* __restrict__ idx,
    float* __restrict__ wts)
{
    const int t = blockIdx.x;
    __shared__ float red[256];
    __shared__ float logits[16];
    const int tid = threadIdx.x;
    const int e = tid >> 4, lane = tid & 15;
    const float* x = h2 + (long)t * 2048;
    float s = 0.f;
    for (int i = lane; i < 2048; i += 16) s += x[i] * gw[e * 2048 + i];
    red[tid] = s; __syncthreads();
    for (int st = 8; st > 0; st >>= 1) {
        if (lane < st) red[tid] += red[tid + st];
        __syncthreads();
    }
    if (lane == 0) logits[e] = red[e * 16] + gb[e];
    __syncthreads();
    if (tid == 0) {
        float m = logits[0];
        for (int j = 1; j < 16; j++) m = fmaxf(m, logits[j]);
        float pr[16]; float sum = 0.f;
        for (int j = 0; j < 16; j++) { pr[j] = expf(logits[j] - m); sum += pr[j]; }
        float inv = 1.f / sum;
        for (int j = 0; j < 16; j++) pr[j] *= inv;
        int i1 = 0; float v1 = -1e30f;
        for (int j = 0; j < 16; j++) { float v = pr[j] + gb[j]; if (v > v1) { v1 = v; i1 = j; } }
        int i2 = 0; float v2 = -1e30f;
        for (int j = 0; j < 16; j++) { if (j == i1) continue; float v = pr[j] + gb[j]; if (v > v2) { v2 = v; i2 = j; } }
        idx[t * 2 + 0] = i1; idx[t * 2 + 1] = i2;
        wts[t * 2 + 0] = pr[i1]; wts[t * 2 + 1] = pr[i2];
    }
}

// ---------------------------------------------------------------------------
// Route: counting sort by expert + tile map (tiles of <=64 slots).
// ---------------------------------------------------------------------------
__global__ __launch_bounds__(256) void route_kernel(
    const int* __restrict__ idx, const float* __restrict__ wts,
    int* __restrict__ slot_te, float* __restrict__ slot_w,
    int* __restrict__ tile_e, int* __restrict__ tile_row0,
    int* __restrict__ tile_cnt, int* __restrict__ n_tiles)
{
    __shared__ int counts[16], offs[16], cursor[16];
    const int tid = threadIdx.x;
    if (tid < 16) { counts[tid] = 0; cursor[tid] = 0; }
    __syncthreads();
    for (int a = tid; a < 2 * T_; a += 256) atomicAdd(&counts[idx[a]], 1);
    __syncthreads();
    if (tid == 0) {
        int o = 0;
        for (int e = 0; e < 16; e++) { offs[e] = o; o += counts[e]; }
        int nt = 0;
        for (int e = 0; e < 16; e++) {
            for (int r0 = 0; r0 < counts[e]; r0 += 64) {
                tile_e[nt] = e;
                tile_row0[nt] = offs[e] + r0;
                int c = counts[e] - r0;
                tile_cnt[nt] = c < 64 ? c : 64;
                nt++;
            }
        }
        *n_tiles = nt;
    }
    __syncthreads();
    for (int a = tid; a < 2 * T_; a += 256) {
        int e = idx[a];
        int pos = offs[e] + atomicAdd(&cursor[e], 1);
        int t = a >> 1, k = a & 1;
        slot_te[pos * 2 + 0] = (t << 1) | k;
        slot_te[pos * 2 + 1] = e;
        slot_w[pos] = wts[a];
    }
}

// ---------------------------------------------------------------------------
// MoE stage 1 (MFMA bf16x3): tile = 64 slots x 128 mi-cols. 4 waves, each
// 64(M) x 32(N). G[slot,i] = silu(x@W1^T+b1) * (x@W3^T+b3).
// Grid: (MI/128, MAX_TILES).
// ---------------------------------------------------------------------------
__global__ __launch_bounds__(256) void moe_mlp13_kernel(
    const float* __restrict__ h2,
    const int* __restrict__ slot_te,
    const int* __restrict__ tile_e, const int* __restrict__ tile_row0,
    const int* __restrict__ tile_cnt, const int* __restrict__ n_tiles,
    const float* __restrict__ w1, const float* __restrict__ b1,
    const float* __restrict__ w3, const float* __restrict__ b3,
    float* __restrict__ G)
{
    const int tile = blockIdx.y;
    if (tile >= *n_tiles) return;
    const int e    = tile_e[tile];
    const int row0 = tile_row0[tile];
    const int tcnt = tile_cnt[tile];
    const int n0   = blockIdx.x * 128;

    __shared__ unsigned short Ah[64][40],  Al[64][40];
    __shared__ unsigned short B1h[128][40], B1l[128][40];
    __shared__ unsigned short B3h[128][40], B3l[128][40];
    __shared__ int tok[64];

    const int tid  = threadIdx.x;
    const int lane = tid & 63;
    const int wv   = tid >> 6;           // wave 0..3 -> N offset wv*32
    const int r16 = lane & 15, g4 = lane >> 4;

    if (tid < 64) {
        int r = tid < tcnt ? tid : tcnt - 1;
        tok[tid] = slot_te[(row0 + r) * 2 + 0] >> 1;
    }
    __syncthreads();

    const float* W1 = w1 + (long)e * MI_ * 2048;
    const float* W3 = w3 + (long)e * MI_ * 2048;

    f32x4_t acc1[4][2], acc3[4][2];
    #pragma unroll
    for (int i = 0; i < 4; i++)
        #pragma unroll
        for (int j = 0; j < 2; j++) {
            acc1[i][j] = (f32x4_t){0.f, 0.f, 0.f, 0.f};
            acc3[i][j] = (f32x4_t){0.f, 0.f, 0.f, 0.f};
        }

    const int sr   = tid >> 3;        // 0..31
    const int scol = (tid & 7) * 4;

    for (int kt = 0; kt < 2048; kt += 32) {
        #pragma unroll
        for (int rr = 0; rr < 64; rr += 32) {
            const float4 v = *(const float4*)(h2 + (long)tok[rr + sr] * 2048 + (kt + scol));
            us4_t h, l;
            split_bf(v.x, ((unsigned short*)&h)[0], ((unsigned short*)&l)[0]);
            split_bf(v.y, ((unsigned short*)&h)[1], ((unsigned short*)&l)[1]);
            split_bf(v.z, ((unsigned short*)&h)[2], ((unsigned short*)&l)[2]);
            split_bf(v.w, ((unsigned short*)&h)[3], ((unsigned short*)&l)[3]);
            *(us4_t*)&Ah[rr + sr][scol] = h;
            *(us4_t*)&Al[rr + sr][scol] = l;
        }
        #pragma unroll
        for (int rr = 0; rr < 128; rr += 32) {
            const long woff = (long)(n0 + rr + sr) * 2048 + (kt + scol);
            {
                const float4 v = *(const float4*)(W1 + woff);
                us4_t h, l;
                split_bf(v.x, ((unsigned short*)&h)[0], ((unsigned short*)&l)[0]);
                split_bf(v.y, ((unsigned short*)&h)[1], ((unsigned short*)&l)[1]);
                split_bf(v.z, ((unsigned short*)&h)[2], ((unsigned short*)&l)[2]);
                split_bf(v.w, ((unsigned short*)&h)[3], ((unsigned short*)&l)[3]);
                *(us4_t*)&B1h[rr + sr][scol] = h;
                *(us4_t*)&B1l[rr + sr][scol] = l;
            }
            {
                const float4 v = *(const float4*)(W3 + woff);
                us4_t h, l;
                split_bf(v.x, ((unsigned short*)&h)[0], ((unsigned short*)&l)[0]);
                split_bf(v.y, ((unsigned short*)&h)[1], ((unsigned short*)&l)[1]);
                split_bf(v.z, ((unsigned short*)&h)[2], ((unsigned short*)&l)[2]);
                split_bf(v.w, ((unsigned short*)&h)[3], ((unsigned short*)&l)[3]);
                *(us4_t*)&B3h[rr + sr][scol] = h;
                *(us4_t*)&B3l[rr + sr][scol] = l;
            }
        }
        __syncthreads();

        bf16x8_t ah[4], al[4], b1h[2], b1l[2], b3h[2], b3l[2];
        #pragma unroll
        for (int i = 0; i < 4; i++) {
            ah[i] = *(const bf16x8_t*)&Ah[i * 16 + r16][g4 * 8];
            al[i] = *(const bf16x8_t*)&Al[i * 16 + r16][g4 * 8];
        }
        #pragma unroll
        for (int j = 0; j < 2; j++) {
            const int cn = wv * 32 + j * 16 + r16;
            b1h[j] = *(const bf16x8_t*)&B1h[cn][g4 * 8];
            b1l[j] = *(const bf16x8_t*)&B1l[cn][g4 * 8];
            b3h[j] = *(const bf16x8_t*)&B3h[cn][g4 * 8];
            b3l[j] = *(const bf16x8_t*)&B3l[cn][g4 * 8];
        }
        #pragma unroll
        for (int i = 0; i < 4; i++)
            #pragma unroll
            for (int j = 0; j < 2; j++) {
                f32x4_t t = acc1[i][j];
                t = __builtin_amdgcn_mfma_f32_16x16x32_bf16(ah[i], b1h[j], t, 0, 0, 0);
                t = __builtin_amdgcn_mfma_f32_16x16x32_bf16(ah[i], b1l[j], t, 0, 0, 0);
                t = __builtin_amdgcn_mfma_f32_16x16x32_bf16(al[i], b1h[j], t, 0, 0, 0);
                acc1[i][j] = t;
                f32x4_t u = acc3[i][j];
                u = __builtin_amdgcn_mfma_f32_16x16x32_bf16(ah[i], b3h[j], u, 0, 0, 0);
                u = __builtin_amdgcn_mfma_f32_16x16x32_bf16(ah[i], b3l[j], u, 0, 0, 0);
                u = __builtin_amdgcn_mfma_f32_16x16x32_bf16(al[i], b3h[j], u, 0, 0, 0);
                acc3[i][j] = u;
            }
        __syncthreads();
    }

    #pragma unroll
    for (int i = 0; i < 4; i++)
        #pragma unroll
        for (int rr = 0; rr < 4; rr++) {
            const int rl = i * 16 + g4 * 4 + rr;
            if (rl >= tcnt) continue;
            const long grow = (long)(row0 + rl) * MI_;
            #pragma unroll
            for (int j = 0; j < 2; j++) {
                const int n = n0 + wv * 32 + j * 16 + r16;
                float a = acc1[i][j][rr] + b1[e * MI_ + n];
                float b = acc3[i][j][rr] + b3[e * MI_ + n];
                G[grow + n] = (a / (1.f + expf(-a))) * b;
            }
        }
}

// ---------------------------------------------------------------------------
// MoE stage 2 (MFMA bf16x3): Y[slot,d] = wgt*(G[slot]@W2^T + b2), scattered
// to y0/y1. Tile = 64 slots x 128 d-cols. Grid: (D/128, MAX_TILES).
// ---------------------------------------------------------------------------
__global__ __launch_bounds__(256) void moe_mlp2_kernel(
    const float* __restrict__ G,
    const int* __restrict__ slot_te, const float* __restrict__ slot_w,
    const int* __restrict__ tile_e, const int* __restrict__ tile_row0,
    const int* __restrict__ tile_cnt, const int* __restrict__ n_tiles,
    const float* __restrict__ w2, const float* __restrict__ b2,
    float* __restrict__ y0, float* __restrict__ y1)
{
    const int tile = blockIdx.y;
    if (tile >= *n_tiles) return;
    const int e    = tile_e[tile];
    const int row0 = tile_row0[tile];
    const int tcnt = tile_cnt[tile];
    const int n0   = blockIdx.x * 128;

    __shared__ unsigned short Ah[64][40], Al[64][40];
    __shared__ unsigned short Bh[128][40], Bl[128][40];
    __shared__ int rsrc[64];

    const int tid  = threadIdx.x;
    const int lane = tid & 63;
    const int wv   = tid >> 6;
    const int r16 = lane & 15, g4 = lane >> 4;

    if (tid < 64) {
        int r = tid < tcnt ? tid : tcnt - 1;
        rsrc[tid] = row0 + r;
    }
    __syncthreads();

    const float* W2 = w2 + (long)e * 2048 * MI_;

    f32x4_t acc[4][2];
    #pragma unroll
    for (int i = 0; i < 4; i++)
        #pragma unroll
        for (int j = 0; j < 2; j++) acc[i][j] = (f32x4_t){0.f, 0.f, 0.f, 0.f};

    const int sr   = tid >> 3;
    const int scol = (tid & 7) * 4;

    for (int kt = 0; kt < MI_; kt += 32) {
        #pragma unroll
        for (int rr = 0; rr < 64; rr += 32) {
            const float4 v = *(const float4*)(G + (long)rsrc[rr + sr] * MI_ + (kt + scol));
            us4_t h, l;
            split_bf(v.x, ((unsigned short*)&h)[0], ((unsigned short*)&l)[0]);
            split_bf(v.y, ((unsigned short*)&h)[1], ((unsigned short*)&l)[1]);
            split_bf(v.z, ((unsigned short*)&h)[2], ((unsigned short*)&l)[2]);
            split_bf(v.w, ((unsigned short*)&h)[3], ((unsigned short*)&l)[3]);
            *(us4_t*)&Ah[rr + sr][scol] = h;
            *(us4_t*)&Al[rr + sr][scol] = l;
        }
        #pragma unroll
        for (int rr = 0; rr < 128; rr += 32) {
            const float4 v = *(const float4*)(W2 + (long)(n0 + rr + sr) * MI_ + (kt + scol));
            us4_t h, l;
            split_bf(v.x, ((unsigned short*)&h)[0], ((unsigned short*)&l)[0]);
            split_bf(v.y, ((unsigned short*)&h)[1], ((unsigned short*)&l)[1]);
            split_bf(v.z, ((unsigned short*)&h)[2], ((unsigned short*)&l)[2]);
            split_bf(v.w, ((unsigned short*)&h)[3], ((unsigned short*)&l)[3]);
            *(us4_t*)&Bh[rr + sr][scol] = h;
            *(us4_t*)&Bl[rr + sr][scol] = l;
        }
        __syncthreads();

        bf16x8_t ah[4], al[4], bh[2], bl[2];
        #pragma unroll
        for (int i = 0; i < 4; i++) {
            ah[i] = *(const bf16x8_t*)&Ah[i * 16 + r16][g4 * 8];
            al[i] = *(const bf16x8_t*)&Al[i * 16 + r16][g4 * 8];
        }
        #pragma unroll
        for (int j = 0; j < 2; j++) {
            const int cn = wv * 32 + j * 16 + r16;
            bh[j] = *(const bf16x8_t*)&Bh[cn][g4 * 8];
            bl[j] = *(const bf16x8_t*)&Bl[cn][g4 * 8];
        }
        #pragma unroll
        for (int i = 0; i < 4; i++)
            #pragma unroll
            for (int j = 0; j < 2; j++) {
                f32x4_t t = acc[i][j];
                t = __builtin_amdgcn_mfma_f32_16x16x32_bf16(ah[i], bh[j], t, 0, 0, 0);
                t = __builtin_amdgcn_mfma_f32_16x16x32_bf16(ah[i], bl[j], t, 0, 0, 0);
                t = __builtin_amdgcn_mfma_f32_16x16x32_bf16(al[i], bh[j], t, 0, 0, 0);
                acc[i][j] = t;
            }
        __syncthreads();
    }

    #pragma unroll
    for (int i = 0; i < 4; i++)
        #pragma unroll
        for (int rr = 0; rr < 4; rr++) {
            const int rl = i * 16 + g4 * 4 + rr;
            if (rl >= tcnt) continue;
            const int slot = row0 + rl;
            const int tk = slot_te[slot * 2 + 0];
            const int t = tk >> 1, k = tk & 1;
            const float wgt = slot_w[slot];
            float* y = (k ? y1 : y0) + (long)t * 2048;
            #pragma unroll
            for (int j = 0; j < 2; j++) {
                const int n = n0 + wv * 32 + j * 16 + r16;
                y[n] = wgt * (acc[i][j][rr] + b2[e * 2048 + n]);
            }
        }
}

// ---------------------------------------------------------------------------
// u1 = silu(u1) * u3
// ---------------------------------------------------------------------------
__global__ void silu_mul_kernel(float* __restrict__ u1,
                                const float* __restrict__ u3, long n)
{
    long i = (long)blockIdx.x * 256 + threadIdx.x;
    if (i >= n) return;
    float a = u1[i];
    u1[i] = (a / (1.f + expf(-a))) * u3[i];
}

// ---------------------------------------------------------------------------
// out = x2 + h2 + y0 + y1 + z
// ---------------------------------------------------------------------------
__global__ void final_add_kernel(const float* __restrict__ x2,
                                 const float* __restrict__ h2,
                                 const float* __restrict__ y0,
                                 const float* __restrict__ y1,
                                 const float* __restrict__ z,
                                 float* __restrict__ out, long n)
{
    long i = (long)blockIdx.x * 256 + threadIdx.x;
    if (i >= n) return;
    out[i] = x2[i] + h2[i] + y0[i] + y1[i] + z[i];
}

// ---------------------------------------------------------------------------
extern "C" void kernel_launch(void* const* d_in, const int* in_sizes, int n_in,
                              void* d_out, int out_size, void* d_ws, size_t ws_size,
                              hipStream_t stream)
{
    (void)in_sizes; (void)n_in; (void)out_size; (void)ws_size;

    const float* x          = (const float*)d_in[0];
    const float* attn_nw    = (const float*)d_in[1];
    const float* ffn_nw     = (const float*)d_in[2];
    const float* wq_a_w     = (const float*)d_in[3];
    const float* wq_a_b     = (const float*)d_in[4];
    const float* q_norm_w   = (const float*)d_in[5];
    const float* wq_b_w     = (const float*)d_in[6];
    const float* wq_b_b     = (const float*)d_in[7];
    const float* wkv_a_w    = (const float*)d_in[8];
    const float* wkv_a_b    = (const float*)d_in[9];
    const float* kv_norm_w  = (const float*)d_in[10];
    const float* wkv_b_w    = (const float*)d_in[11];
    const float* wo_w       = (const float*)d_in[12];
    const float* wo_b       = (const float*)d_in[13];
    const float* gate_w     = (const float*)d_in[14];
    const float* gate_b     = (const float*)d_in[15];
    const float* e_w1       = (const float*)d_in[16];
    const float* e_b1       = (const float*)d_in[17];
    const float* e_w2       = (const float*)d_in[18];
    const float* e_b2       = (const float*)d_in[19];
    const float* e_w3       = (const float*)d_in[20];
    const float* e_b3       = (const float*)d_in[21];
    const float* s_w1       = (const float*)d_in[22];
    const float* s_b1       = (const float*)d_in[23];
    const float* s_w2       = (const float*)d_in[24];
    const float* s_b2       = (const float*)d_in[25];
    const float* s_w3       = (const float*)d_in[26];
    const float* s_b3       = (const float*)d_in[27];
    const float* cosb       = (const float*)d_in[28];
    const float* sinb       = (const float*)d_in[29];

    float* ws = (float*)d_ws;
    // Workspace layout (floats)
    float* h    = ws + 0;            // T*2048          (reused later as y0)
    float* qa   = ws + 4194304;      // T*1536
    float* q    = ws + 7340032;      // T*3072          (reused later as y1)
    float* kvf  = ws + 13631488;     // T*576
    float* qabs = ws + 14811136;     // T*H*512 = 16.8M (q_abs, then o, then G)
    float* o2   = ws + 31588352;     // T*2048
    float* x2   = ws + 35782656;     // T*2048
    float* h2   = ws + 39976960;     // T*2048
    float* u1   = ws + 44171264;     // T*2816
    float* u3   = ws + 49938432;     // T*2816          (reused later as z)
    float* wts  = ws + 55705600;     // T*2 floats
    int*   idx  = (int*)(ws + 55709696);     // T*2 ints
    int*   slot_te = (int*)(ws + 55713792);  // 2T*2 ints
    float* slot_w  = ws + 55721984;          // 2T floats
    float* y0 = h;
    float* y1 = q;
    float* z  = u3;

    // Attention scores scratch: [H][S][S] per batch = 16.8M floats, in the
    // dead-until-step-10 o2/x2/h2/u1 region.
    float* scores = o2;

    // MoE scratch inside the (dead after step 10) qabs region:
    float* G = qabs;                              // 2T * MI = 5,767,168 floats
    int* tile_e    = (int*)(qabs + 5767168);
    int* tile_row0 = tile_e + MAX_TILES_;
    int* tile_cnt  = tile_e + 2 * MAX_TILES_;
    int* n_tiles   = tile_e + 3 * MAX_TILES_;

    // 1. h = rms(x, attn_norm_w)
    rms_kernel<<<dim3(T_), 256, 0, stream>>>(x, h, attn_nw, 2048, 2048, 2048);

    // 2. qa = h @ wq_a_w^T + wq_a_b            [T,1536]
    gemm_mfma_kernel<<<dim3(QLR_ / 128, T_ / 128, 1), 256, 0, stream>>>(
        h, 2048, 0, wq_a_w, 2048, 0, 0, wq_a_b, 0,
        nullptr, 0, 0, qa, QLR_, 0, T_, QLR_, 2048);

    // 3. qa = rms(qa, q_norm_w) in place
    rms_kernel<<<dim3(T_), 256, 0, stream>>>(qa, qa, q_norm_w, QLR_, QLR_, QLR_);

    // 4. q = qa @ wq_b_w^T + wq_b_b            [T, 3072]
    gemm_mfma_kernel<<<dim3(H_ * QKD_ / 128, T_ / 128, 1), 256, 0, stream>>>(
        qa, QLR_, 0, wq_b_w, QLR_, 0, 0, wq_b_b, 0,
        nullptr, 0, 0, q, H_ * QKD_, 0, T_, H_ * QKD_, QLR_);

    // 5. kvf = h @ wkv_a_w^T + wkv_a_b         [T, 576]  (N%128!=0 -> legacy)
    gemm_kernel<<<dim3((KVR_ + ROPE_) / 64, T_ / 64, 1), 256, 0, stream>>>(
        h, 2048, 0, wkv_a_w, 2048, 0, 0, wkv_a_b, 0,
        nullptr, 0, 0, kvf, KVR_ + ROPE_, 0, T_, KVR_ + ROPE_, 2048);

    // 6. RoPE on q_pe (in q) and k_pe (in kvf), in place
    {
        int total_q = T_ * H_ * 32;
        rope_kernel<<<dim3((total_q + 255) / 256), 256, 0, stream>>>(
            q, cosb, sinb, H_, H_ * QKD_, QKD_, NOPE_, total_q);
        int total_k = T_ * 32;
        rope_kernel<<<dim3((total_k + 255) / 256), 256, 0, stream>>>(
            kvf, cosb, sinb, 1, KVR_ + ROPE_, 0, KVR_, total_k);
    }

    // 7. kv_n = rms(kv, kv_norm_w) in place in kvf[:, :512]
    rms_kernel<<<dim3(T_), 256, 0, stream>>>(kvf, kvf, kv_norm_w, KVR_,
                                             KVR_ + ROPE_, KVR_ + ROPE_);

    // 8. q_abs[t,h,:] = q_nope[t,h,:] @ wb1[h]  (W [K=128,N=512] per head)
    gemm_mfma_kernel<<<dim3(KVR_ / 128, T_ / 128, H_), 256, 0, stream>>>(
        q, H_ * QKD_, QKD_,
        wkv_b_w, KVR_, (long)256 * KVR_, 1,
        nullptr, 0, nullptr, 0, 0,
        qabs, H_ * KVR_, KVR_, T_, KVR_, NOPE_);

    // 9. attention as batched GEMMs per batch b
    for (int b = 0; b < B_; b++) {
        const float* kvb = kvf + (long)b * S_ * (KVR_ + ROPE_);
        // 9a. scores = q_abs . kv_n^T       (M=S, N=S, K=512, z=heads)
        gemm_mfma_kernel<<<dim3(S_ / 128, S_ / 128, H_), 256, 0, stream>>>(
            qabs + (long)b * S_ * H_ * KVR_, H_ * KVR_, KVR_,
            kvb, KVR_ + ROPE_, 0, 0,
            nullptr, 0, nullptr, 0, 0,
            scores, S_, (long)S_ * S_, S_, S_, KVR_);
        // 9b. scores += q_pe . k_pe^T       (K=64, res-accumulate)
        gemm_mfma_kernel<<<dim3(S_ / 128, S_ / 128, H_), 256, 0, stream>>>(
            q + (long)b * S_ * H_ * QKD_ + NOPE_, H_ * QKD_, QKD_,
            kvb + KVR_, KVR_ + ROPE_, 0, 0,
            nullptr, 0, scores, S_, (long)S_ * S_,
            scores, S_, (long)S_ * S_, S_, S_, ROPE_);
        // 9c. softmax rows (SCALE folded in)
        softmax_kernel<<<dim3(H_ * S_), 256, 0, stream>>>(scores);
        // 9d. o = P @ kv_n                  (M=S, N=512, K=S, W[K,N])
        gemm_mfma_kernel<<<dim3(KVR_ / 128, S_ / 128, H_), 256, 0, stream>>>(
            scores, S_, (long)S_ * S_,
            kvb, KVR_ + ROPE_, 0, 1,
            nullptr, 0, nullptr, 0, 0,
            qabs + (long)b * S_ * H_ * KVR_, H_ * KVR_, KVR_, S_, KVR_, S_);
    }

    // 10. o2[t,h,:] = o[t,h,:] @ wb2[h]^T
    gemm_mfma_kernel<<<dim3(VD_ / 128, T_ / 128, H_), 256, 0, stream>>>(
        qabs, H_ * KVR_, KVR_,
        wkv_b_w + (long)NOPE_ * KVR_, KVR_, (long)256 * KVR_, 0,
        nullptr, 0, nullptr, 0, 0,
        o2, H_ * VD_, VD_, T_, VD_, KVR_);

    // 11. x2 = x + o2 @ wo_w^T + wo_b
    gemm_mfma_kernel<<<dim3(D_ / 128, T_ / 128, 1), 256, 0, stream>>>(
        o2, 2048, 0, wo_w, 2048, 0, 0, wo_b, 0,
        x, 2048, 0, x2, 2048, 0, T_, D_, 2048);

    // 12. h2 = rms(x2, ffn_norm_w)
    rms_kernel<<<dim3(T_), 256, 0, stream>>>(x2, h2, ffn_nw, 2048, 2048, 2048);

    // 13. gate -> top2
    gate_kernel<<<dim3(T_), 256, 0, stream>>>(h2, gate_w, gate_b, idx, wts);

    // 14. route
    route_kernel<<<dim3(1), 256, 0, stream>>>(idx, wts, slot_te, slot_w,
                                              tile_e, tile_row0, tile_cnt, n_tiles);

    // 15. MoE batched per-expert MFMA GEMMs
    moe_mlp13_kernel<<<dim3(MI_ / 128, MAX_TILES_), 256, 0, stream>>>(
        h2, slot_te, tile_e, tile_row0, tile_cnt, n_tiles,
        e_w1, e_b1, e_w3, e_b3, G);
    moe_mlp2_kernel<<<dim3(D_ / 128, MAX_TILES_), 256, 0, stream>>>(
        G, slot_te, slot_w, tile_e, tile_row0, tile_cnt, n_tiles,
        e_w2, e_b2, y0, y1);

    // 16. shared MLP
    gemm_mfma_kernel<<<dim3(SMI_ / 128, T_ / 128, 1), 256, 0, stream>>>(
        h2, 2048, 0, s_w1, 2048, 0, 0, s_b1, 0,
        nullptr, 0, 0, u1, SMI_, 0, T_, SMI_, 2048);
    gemm_mfma_kernel<<<dim3(SMI_ / 128, T_ / 128, 1), 256, 0, stream>>>(
        h2, 2048, 0, s_w3, 2048, 0, 0, s_b3, 0,
        nullptr, 0, 0, u3, SMI_, 0, T_, SMI_, 2048);
    {
        long n = (long)T_ * SMI_;
        silu_mul_kernel<<<dim3((unsigned)((n + 255) / 256)), 256, 0, stream>>>(u1, u3, n);
    }
    gemm_mfma_kernel<<<dim3(D_ / 128, T_ / 128, 1), 256, 0, stream>>>(
        u1, SMI_, 0, s_w2, SMI_, 0, 0, s_b2, 0,
        nullptr, 0, 0, z, D_, 0, T_, D_, SMI_);

    // 17. out = x2 + h2 + y0 + y1 + z
    {
        long n = (long)T_ * D_;
        final_add_kernel<<<dim3((unsigned)((n + 255) / 256)), 256, 0, stream>>>(
            x2, h2, y0, y1, z, (float*)d_out, n);
    }
}

// Round 4
// 2683.633 us; speedup vs baseline: 16.2658x; 1.0210x over previous
//
#include <hip/hip_runtime.h>
#include <math.h>

// Problem constants
constexpr int B_ = 2, S_ = 1024, D_ = 2048, H_ = 16;
constexpr int NOPE_ = 128, ROPE_ = 64, VD_ = 128, KVR_ = 512, QLR_ = 1536;
constexpr int NE_ = 16, MI_ = 1408, SMI_ = 2816;
constexpr int QKD_ = NOPE_ + ROPE_;            // 192
constexpr int T_ = B_ * S_;                    // 2048
constexpr float SCALE_ = 0.07216878364870322f; // 192^-0.5
constexpr float EPS_ = 1e-3f;
constexpr int MAX_TILES_ = 80;                 // sum_e ceil(n_e/64) <= 79

typedef __attribute__((ext_vector_type(8))) short  bf16x8_t;
typedef __attribute__((ext_vector_type(4))) float  f32x4_t;
typedef __attribute__((ext_vector_type(4))) unsigned short us4_t;

// Cheap fp32 -> bf16 hi + bf16 lo split (truncation; lo captures hi's
// truncation error exactly, truncating lo adds ~2^-17 rel).  4 VALU ops.
__device__ __forceinline__ void split_bf(float v, unsigned short& h, unsigned short& l)
{
    unsigned int u = __float_as_uint(v);
    h = (unsigned short)(u >> 16);
    float lo = v - __uint_as_float(u & 0xFFFF0000u);
    l = (unsigned short)(__float_as_uint(lo) >> 16);
}

__device__ __forceinline__ void split4(const float4& v, us4_t& h, us4_t& l)
{
    split_bf(v.x, ((unsigned short*)&h)[0], ((unsigned short*)&l)[0]);
    split_bf(v.y, ((unsigned short*)&h)[1], ((unsigned short*)&l)[1]);
    split_bf(v.z, ((unsigned short*)&h)[2], ((unsigned short*)&l)[2]);
    split_bf(v.w, ((unsigned short*)&h)[3], ((unsigned short*)&l)[3]);
}

// Stage 128 rows x 32 cols of fp32 P (row-major, leading dim ldp) into
// hi/lo bf16 LDS tiles. rowclamp clamps the source row (for N%128!=0).
__device__ __forceinline__ void stage_rows(
    const float* __restrict__ P, int ldp, int row0, int rowclamp,
    int kt, int sr, int scol,
    unsigned short (*__restrict__ Hs)[40], unsigned short (*__restrict__ Ls)[40])
{
    #pragma unroll
    for (int rr = 0; rr < 128; rr += 32) {
        int row = row0 + rr + sr;
        if (row > rowclamp) row = rowclamp;
        const float4 v = *(const float4*)(P + (long)row * ldp + (kt + scol));
        us4_t h, l;
        split4(v, h, l);
        *(us4_t*)&Hs[rr + sr][scol] = h;
        *(us4_t*)&Ls[rr + sr][scol] = l;
    }
}

// ---------------------------------------------------------------------------
// MFMA bf16x3 GEMM: C = A@W^T (+ optional 2nd K-block A2@W2^T) + bias + res.
// 128x128 tile, BK=32, 4 waves (2x2) each 64x64. fp32 accumulate, bf16x3
// (hi*hi + hi*lo + lo*hi). M%128==0, K%32==0, K2%32==0. N tiles padded to
// 128 with Nlim clamping/guarding. w_kn: 0 -> W[N,K], 1 -> W[K,N] (LDS
// transpose; only for the primary K-block). res_mode: 0 none, 1 add res,
// 2 C = silu(res) * (acc+bias).
// ---------------------------------------------------------------------------
__global__ __launch_bounds__(256) void gemm_mfma_kernel(
    const float* __restrict__ A, int lda, long strideA,
    const float* __restrict__ W, int ldw, long strideW, int w_kn,
    const float* __restrict__ A2, int lda2, long strideA2,
    const float* __restrict__ W2, int ldw2, long strideW2, int K2,
    const float* __restrict__ bias, long strideBias,
    const float* __restrict__ res, int ldr, long strideRes, int res_mode,
    float* __restrict__ C, int ldc, long strideC,
    int Nlim, int K)
{
    const int bz = blockIdx.z;
    A += (long)bz * strideA;
    W += (long)bz * strideW;
    C += (long)bz * strideC;
    if (A2)   A2  += (long)bz * strideA2;
    if (W2)   W2  += (long)bz * strideW2;
    if (bias) bias += (long)bz * strideBias;
    if (res)  res  += (long)bz * strideRes;

    __shared__ unsigned short Ah[128][40], Al[128][40];
    __shared__ unsigned short Bh[128][40], Bl[128][40];

    const int m0 = blockIdx.y * 128;
    const int n0 = blockIdx.x * 128;
    const int tid  = threadIdx.x;
    const int lane = tid & 63;
    const int wv   = tid >> 6;
    const int wm = (wv >> 1) * 64, wn = (wv & 1) * 64;
    const int r16 = lane & 15, g4 = lane >> 4;

    f32x4_t acc[4][4];
    #pragma unroll
    for (int i = 0; i < 4; i++)
        #pragma unroll
        for (int j = 0; j < 4; j++) acc[i][j] = (f32x4_t){0.f, 0.f, 0.f, 0.f};

    const int sr   = tid >> 3;        // 0..31
    const int scol = (tid & 7) * 4;   // 0,4,..,28
    const int tcol = tid & 63, tkr = tid >> 6;

    for (int kt = 0; kt < K; kt += 32) {
        stage_rows(A, lda, m0, 1 << 30, kt, sr, scol, Ah, Al);
        if (w_kn == 0) {
            stage_rows(W, ldw, n0, Nlim - 1, kt, sr, scol, Bh, Bl);
        } else {
            #pragma unroll
            for (int cb = 0; cb < 128; cb += 64)
                #pragma unroll
                for (int kb = 0; kb < 32; kb += 4) {
                    float v = W[(long)(kt + kb + tkr) * ldw + (n0 + cb + tcol)];
                    unsigned short h, l;
                    split_bf(v, h, l);
                    Bh[cb + tcol][kb + tkr] = h;
                    Bl[cb + tcol][kb + tkr] = l;
                }
        }
        __syncthreads();

        bf16x8_t ah[4], al[4], bh[4], bl[4];
        #pragma unroll
        for (int i = 0; i < 4; i++) {
            ah[i] = *(const bf16x8_t*)&Ah[wm + i * 16 + r16][g4 * 8];
            al[i] = *(const bf16x8_t*)&Al[wm + i * 16 + r16][g4 * 8];
            bh[i] = *(const bf16x8_t*)&Bh[wn + i * 16 + r16][g4 * 8];
            bl[i] = *(const bf16x8_t*)&Bl[wn + i * 16 + r16][g4 * 8];
        }
        #pragma unroll
        for (int i = 0; i < 4; i++)
            #pragma unroll
            for (int j = 0; j < 4; j++) {
                f32x4_t t = acc[i][j];
                t = __builtin_amdgcn_mfma_f32_16x16x32_bf16(ah[i], bh[j], t, 0, 0, 0);
                t = __builtin_amdgcn_mfma_f32_16x16x32_bf16(ah[i], bl[j], t, 0, 0, 0);
                t = __builtin_amdgcn_mfma_f32_16x16x32_bf16(al[i], bh[j], t, 0, 0, 0);
                acc[i][j] = t;
            }
        __syncthreads();
    }

    // Optional fused second K-block (w_kn==0 layout only).
    if (K2 > 0) {
        for (int kt = 0; kt < K2; kt += 32) {
            stage_rows(A2, lda2, m0, 1 << 30, kt, sr, scol, Ah, Al);
            stage_rows(W2, ldw2, n0, Nlim - 1, kt, sr, scol, Bh, Bl);
            __syncthreads();
            bf16x8_t ah[4], al[4], bh[4], bl[4];
            #pragma unroll
            for (int i = 0; i < 4; i++) {
                ah[i] = *(const bf16x8_t*)&Ah[wm + i * 16 + r16][g4 * 8];
                al[i] = *(const bf16x8_t*)&Al[wm + i * 16 + r16][g4 * 8];
                bh[i] = *(const bf16x8_t*)&Bh[wn + i * 16 + r16][g4 * 8];
                bl[i] = *(const bf16x8_t*)&Bl[wn + i * 16 + r16][g4 * 8];
            }
            #pragma unroll
            for (int i = 0; i < 4; i++)
                #pragma unroll
                for (int j = 0; j < 4; j++) {
                    f32x4_t t = acc[i][j];
                    t = __builtin_amdgcn_mfma_f32_16x16x32_bf16(ah[i], bh[j], t, 0, 0, 0);
                    t = __builtin_amdgcn_mfma_f32_16x16x32_bf16(ah[i], bl[j], t, 0, 0, 0);
                    t = __builtin_amdgcn_mfma_f32_16x16x32_bf16(al[i], bh[j], t, 0, 0, 0);
                    acc[i][j] = t;
                }
            __syncthreads();
        }
    }

    #pragma unroll
    for (int i = 0; i < 4; i++)
        #pragma unroll
        for (int rr = 0; rr < 4; rr++) {
            const int m = m0 + wm + i * 16 + g4 * 4 + rr;
            #pragma unroll
            for (int j = 0; j < 4; j++) {
                const int n = n0 + wn + j * 16 + r16;
                if (n >= Nlim) continue;
                float v = acc[i][j][rr];
                if (bias) v += bias[n];
                if (res_mode == 1) {
                    v += res[(long)m * ldr + n];
                } else if (res_mode == 2) {
                    float r = res[(long)m * ldr + n];
                    v = (r / (1.f + expf(-r))) * v;
                }
                C[(long)m * ldc + n] = v;
            }
        }
}

// ---------------------------------------------------------------------------
// RMSNorm over rows.
// ---------------------------------------------------------------------------
__global__ __launch_bounds__(256) void rms_kernel(
    const float* __restrict__ in, float* __restrict__ out,
    const float* __restrict__ w, int N, int in_stride, int out_stride)
{
    const int row = blockIdx.x;
    const float* x = in + (long)row * in_stride;
    float* y = out + (long)row * out_stride;
    __shared__ float red[256];
    const int tid = threadIdx.x;
    float s = 0.f;
    for (int i = tid; i < N; i += 256) { float v = x[i]; s += v * v; }
    red[tid] = s; __syncthreads();
    for (int st = 128; st > 0; st >>= 1) {
        if (tid < st) red[tid] += red[tid + st];
        __syncthreads();
    }
    const float scale = rsqrtf(red[0] / (float)N + EPS_);
    for (int i = tid; i < N; i += 256) y[i] = w[i] * x[i] * scale;
}

// ---------------------------------------------------------------------------
// Interleaved RoPE, in place.
// ---------------------------------------------------------------------------
__global__ void rope_kernel(float* __restrict__ p,
                            const float* __restrict__ cosb,
                            const float* __restrict__ sinb,
                            int nheads, int row_stride, int head_stride,
                            int off, int total)
{
    int i = blockIdx.x * 256 + threadIdx.x;
    if (i >= total) return;
    int pair = i & 31;
    int rem = i >> 5;
    int h = rem % nheads;
    int t = rem / nheads;
    int s = t % S_;
    float c = cosb[s * 32 + pair], sn = sinb[s * 32 + pair];
    float* base = p + (long)t * row_stride + (long)h * head_stride + off + pair * 2;
    float x0 = base[0], x1 = base[1];
    base[0] = x0 * c - x1 * sn;
    base[1] = x0 * sn + x1 * c;
}

// ---------------------------------------------------------------------------
// Row softmax over 1024-wide rows, scale folded in.
// ---------------------------------------------------------------------------
__global__ __launch_bounds__(256) void softmax_kernel(float* __restrict__ sc)
{
    float* row = sc + (long)blockIdx.x * 1024;
    const int tid = threadIdx.x;
    __shared__ float red[256];

    float4 v = ((const float4*)row)[tid];
    v.x *= SCALE_; v.y *= SCALE_; v.z *= SCALE_; v.w *= SCALE_;

    float m = fmaxf(fmaxf(v.x, v.y), fmaxf(v.z, v.w));
    red[tid] = m; __syncthreads();
    for (int st = 128; st > 0; st >>= 1) {
        if (tid < st) red[tid] = fmaxf(red[tid], red[tid + st]);
        __syncthreads();
    }
    m = red[0];
    __syncthreads();

    v.x = __expf(v.x - m); v.y = __expf(v.y - m);
    v.z = __expf(v.z - m); v.w = __expf(v.w - m);
    float s = v.x + v.y + v.z + v.w;
    red[tid] = s; __syncthreads();
    for (int st = 128; st > 0; st >>= 1) {
        if (tid < st) red[tid] += red[tid + st];
        __syncthreads();
    }
    const float inv = 1.f / red[0];

    v.x *= inv; v.y *= inv; v.z *= inv; v.w *= inv;
    ((float4*)row)[tid] = v;
}

// ---------------------------------------------------------------------------
// Gate: logits -> softmax -> top2 on (probs + gate_b), weights = probs[idx]
// ---------------------------------------------------------------------------
__global__ __launch_bounds__(256) void gate_kernel(
    const float* __restrict__ h2, const float* __restrict__ gw,
    const float* __restrict__ gb, int* __restrict__ idx,
    float* __restrict__ wts)
{
    const int t = blockIdx.x;
    __shared__ float red[256];
    __shared__ float logits[16];
    const int tid = threadIdx.x;
    const int e = tid >> 4, lane = tid & 15;
    const float* x = h2 + (long)t * 2048;
    float s = 0.f;
    for (int i = lane; i < 2048; i += 16) s += x[i] * gw[e * 2048 + i];
    red[tid] = s; __syncthreads();
    for (int st = 8; st > 0; st >>= 1) {
        if (lane < st) red[tid] += red[tid + st];
        __syncthreads();
    }
    if (lane == 0) logits[e] = red[e * 16] + gb[e];
    __syncthreads();
    if (tid == 0) {
        float m = logits[0];
        for (int j = 1; j < 16; j++) m = fmaxf(m, logits[j]);
        float pr[16]; float sum = 0.f;
        for (int j = 0; j < 16; j++) { pr[j] = expf(logits[j] - m); sum += pr[j]; }
        float inv = 1.f / sum;
        for (int j = 0; j < 16; j++) pr[j] *= inv;
        int i1 = 0; float v1 = -1e30f;
        for (int j = 0; j < 16; j++) { float v = pr[j] + gb[j]; if (v > v1) { v1 = v; i1 = j; } }
        int i2 = 0; float v2 = -1e30f;
        for (int j = 0; j < 16; j++) { if (j == i1) continue; float v = pr[j] + gb[j]; if (v > v2) { v2 = v; i2 = j; } }
        idx[t * 2 + 0] = i1; idx[t * 2 + 1] = i2;
        wts[t * 2 + 0] = pr[i1]; wts[t * 2 + 1] = pr[i2];
    }
}

// ---------------------------------------------------------------------------
// Route: counting sort by expert + tile map (tiles of <=64 slots).
// ---------------------------------------------------------------------------
__global__ __launch_bounds__(256) void route_kernel(
    const int* __restrict__ idx, const float* __restrict__ wts,
    int* __restrict__ slot_te, float* __restrict__ slot_w,
    int* __restrict__ tile_e, int* __restrict__ tile_row0,
    int* __restrict__ tile_cnt, int* __restrict__ n_tiles)
{
    __shared__ int counts[16], offs[16], cursor[16];
    const int tid = threadIdx.x;
    if (tid < 16) { counts[tid] = 0; cursor[tid] = 0; }
    __syncthreads();
    for (int a = tid; a < 2 * T_; a += 256) atomicAdd(&counts[idx[a]], 1);
    __syncthreads();
    if (tid == 0) {
        int o = 0;
        for (int e = 0; e < 16; e++) { offs[e] = o; o += counts[e]; }
        int nt = 0;
        for (int e = 0; e < 16; e++) {
            for (int r0 = 0; r0 < counts[e]; r0 += 64) {
                tile_e[nt] = e;
                tile_row0[nt] = offs[e] + r0;
                int c = counts[e] - r0;
                tile_cnt[nt] = c < 64 ? c : 64;
                nt++;
            }
        }
        *n_tiles = nt;
    }
    __syncthreads();
    for (int a = tid; a < 2 * T_; a += 256) {
        int e = idx[a];
        int pos = offs[e] + atomicAdd(&cursor[e], 1);
        int t = a >> 1, k = a & 1;
        slot_te[pos * 2 + 0] = (t << 1) | k;
        slot_te[pos * 2 + 1] = e;
        slot_w[pos] = wts[a];
    }
}

// ---------------------------------------------------------------------------
// MoE stage 1 (MFMA bf16x3): tile = 64 slots x 128 mi-cols. 4 waves, each
// 64(M) x 32(N). G[slot,i] = silu(x@W1^T+b1) * (x@W3^T+b3).
// Grid: (MI/128, MAX_TILES).
// ---------------------------------------------------------------------------
__global__ __launch_bounds__(256) void moe_mlp13_kernel(
    const float* __restrict__ h2,
    const int* __restrict__ slot_te,
    const int* __restrict__ tile_e, const int* __restrict__ tile_row0,
    const int* __restrict__ tile_cnt, const int* __restrict__ n_tiles,
    const float* __restrict__ w1, const float* __restrict__ b1,
    const float* __restrict__ w3, const float* __restrict__ b3,
    float* __restrict__ G)
{
    const int tile = blockIdx.y;
    if (tile >= *n_tiles) return;
    const int e    = tile_e[tile];
    const int row0 = tile_row0[tile];
    const int tcnt = tile_cnt[tile];
    const int n0   = blockIdx.x * 128;

    __shared__ unsigned short Ah[64][40],  Al[64][40];
    __shared__ unsigned short B1h[128][40], B1l[128][40];
    __shared__ unsigned short B3h[128][40], B3l[128][40];
    __shared__ int tok[64];

    const int tid  = threadIdx.x;
    const int lane = tid & 63;
    const int wv   = tid >> 6;           // wave 0..3 -> N offset wv*32
    const int r16 = lane & 15, g4 = lane >> 4;

    if (tid < 64) {
        int r = tid < tcnt ? tid : tcnt - 1;
        tok[tid] = slot_te[(row0 + r) * 2 + 0] >> 1;
    }
    __syncthreads();

    const float* W1 = w1 + (long)e * MI_ * 2048;
    const float* W3 = w3 + (long)e * MI_ * 2048;

    f32x4_t acc1[4][2], acc3[4][2];
    #pragma unroll
    for (int i = 0; i < 4; i++)
        #pragma unroll
        for (int j = 0; j < 2; j++) {
            acc1[i][j] = (f32x4_t){0.f, 0.f, 0.f, 0.f};
            acc3[i][j] = (f32x4_t){0.f, 0.f, 0.f, 0.f};
        }

    const int sr   = tid >> 3;        // 0..31
    const int scol = (tid & 7) * 4;

    for (int kt = 0; kt < 2048; kt += 32) {
        #pragma unroll
        for (int rr = 0; rr < 64; rr += 32) {
            const float4 v = *(const float4*)(h2 + (long)tok[rr + sr] * 2048 + (kt + scol));
            us4_t h, l;
            split4(v, h, l);
            *(us4_t*)&Ah[rr + sr][scol] = h;
            *(us4_t*)&Al[rr + sr][scol] = l;
        }
        #pragma unroll
        for (int rr = 0; rr < 128; rr += 32) {
            const long woff = (long)(n0 + rr + sr) * 2048 + (kt + scol);
            {
                const float4 v = *(const float4*)(W1 + woff);
                us4_t h, l;
                split4(v, h, l);
                *(us4_t*)&B1h[rr + sr][scol] = h;
                *(us4_t*)&B1l[rr + sr][scol] = l;
            }
            {
                const float4 v = *(const float4*)(W3 + woff);
                us4_t h, l;
                split4(v, h, l);
                *(us4_t*)&B3h[rr + sr][scol] = h;
                *(us4_t*)&B3l[rr + sr][scol] = l;
            }
        }
        __syncthreads();

        bf16x8_t ah[4], al[4], b1h[2], b1l[2], b3h[2], b3l[2];
        #pragma unroll
        for (int i = 0; i < 4; i++) {
            ah[i] = *(const bf16x8_t*)&Ah[i * 16 + r16][g4 * 8];
            al[i] = *(const bf16x8_t*)&Al[i * 16 + r16][g4 * 8];
        }
        #pragma unroll
        for (int j = 0; j < 2; j++) {
            const int cn = wv * 32 + j * 16 + r16;
            b1h[j] = *(const bf16x8_t*)&B1h[cn][g4 * 8];
            b1l[j] = *(const bf16x8_t*)&B1l[cn][g4 * 8];
            b3h[j] = *(const bf16x8_t*)&B3h[cn][g4 * 8];
            b3l[j] = *(const bf16x8_t*)&B3l[cn][g4 * 8];
        }
        #pragma unroll
        for (int i = 0; i < 4; i++)
            #pragma unroll
            for (int j = 0; j < 2; j++) {
                f32x4_t t = acc1[i][j];
                t = __builtin_amdgcn_mfma_f32_16x16x32_bf16(ah[i], b1h[j], t, 0, 0, 0);
                t = __builtin_amdgcn_mfma_f32_16x16x32_bf16(ah[i], b1l[j], t, 0, 0, 0);
                t = __builtin_amdgcn_mfma_f32_16x16x32_bf16(al[i], b1h[j], t, 0, 0, 0);
                acc1[i][j] = t;
                f32x4_t u = acc3[i][j];
                u = __builtin_amdgcn_mfma_f32_16x16x32_bf16(ah[i], b3h[j], u, 0, 0, 0);
                u = __builtin_amdgcn_mfma_f32_16x16x32_bf16(ah[i], b3l[j], u, 0, 0, 0);
                u = __builtin_amdgcn_mfma_f32_16x16x32_bf16(al[i], b3h[j], u, 0, 0, 0);
                acc3[i][j] = u;
            }
        __syncthreads();
    }

    #pragma unroll
    for (int i = 0; i < 4; i++)
        #pragma unroll
        for (int rr = 0; rr < 4; rr++) {
            const int rl = i * 16 + g4 * 4 + rr;
            if (rl >= tcnt) continue;
            const long grow = (long)(row0 + rl) * MI_;
            #pragma unroll
            for (int j = 0; j < 2; j++) {
                const int n = n0 + wv * 32 + j * 16 + r16;
                float a = acc1[i][j][rr] + b1[e * MI_ + n];
                float b = acc3[i][j][rr] + b3[e * MI_ + n];
                G[grow + n] = (a / (1.f + expf(-a))) * b;
            }
        }
}

// ---------------------------------------------------------------------------
// MoE stage 2 (MFMA bf16x3): Y[slot,d] = wgt*(G[slot]@W2^T + b2), scattered
// to y0/y1. Tile = 64 slots x 128 d-cols. Grid: (D/128, MAX_TILES).
// ---------------------------------------------------------------------------
__global__ __launch_bounds__(256) void moe_mlp2_kernel(
    const float* __restrict__ G,
    const int* __restrict__ slot_te, const float* __restrict__ slot_w,
    const int* __restrict__ tile_e, const int* __restrict__ tile_row0,
    const int* __restrict__ tile_cnt, const int* __restrict__ n_tiles,
    const float* __restrict__ w2, const float* __restrict__ b2,
    float* __restrict__ y0, float* __restrict__ y1)
{
    const int tile = blockIdx.y;
    if (tile >= *n_tiles) return;
    const int e    = tile_e[tile];
    const int row0 = tile_row0[tile];
    const int tcnt = tile_cnt[tile];
    const int n0   = blockIdx.x * 128;

    __shared__ unsigned short Ah[64][40], Al[64][40];
    __shared__ unsigned short Bh[128][40], Bl[128][40];
    __shared__ int rsrc[64];

    const int tid  = threadIdx.x;
    const int lane = tid & 63;
    const int wv   = tid >> 6;
    const int r16 = lane & 15, g4 = lane >> 4;

    if (tid < 64) {
        int r = tid < tcnt ? tid : tcnt - 1;
        rsrc[tid] = row0 + r;
    }
    __syncthreads();

    const float* W2 = w2 + (long)e * 2048 * MI_;

    f32x4_t acc[4][2];
    #pragma unroll
    for (int i = 0; i < 4; i++)
        #pragma unroll
        for (int j = 0; j < 2; j++) acc[i][j] = (f32x4_t){0.f, 0.f, 0.f, 0.f};

    const int sr   = tid >> 3;
    const int scol = (tid & 7) * 4;

    for (int kt = 0; kt < MI_; kt += 32) {
        #pragma unroll
        for (int rr = 0; rr < 64; rr += 32) {
            const float4 v = *(const float4*)(G + (long)rsrc[rr + sr] * MI_ + (kt + scol));
            us4_t h, l;
            split4(v, h, l);
            *(us4_t*)&Ah[rr + sr][scol] = h;
            *(us4_t*)&Al[rr + sr][scol] = l;
        }
        #pragma unroll
        for (int rr = 0; rr < 128; rr += 32) {
            const float4 v = *(const float4*)(W2 + (long)(n0 + rr + sr) * MI_ + (kt + scol));
            us4_t h, l;
            split4(v, h, l);
            *(us4_t*)&Bh[rr + sr][scol] = h;
            *(us4_t*)&Bl[rr + sr][scol] = l;
        }
        __syncthreads();

        bf16x8_t ah[4], al[4], bh[2], bl[2];
        #pragma unroll
        for (int i = 0; i < 4; i++) {
            ah[i] = *(const bf16x8_t*)&Ah[i * 16 + r16][g4 * 8];
            al[i] = *(const bf16x8_t*)&Al[i * 16 + r16][g4 * 8];
        }
        #pragma unroll
        for (int j = 0; j < 2; j++) {
            const int cn = wv * 32 + j * 16 + r16;
            bh[j] = *(const bf16x8_t*)&Bh[cn][g4 * 8];
            bl[j] = *(const bf16x8_t*)&Bl[cn][g4 * 8];
        }
        #pragma unroll
        for (int i = 0; i < 4; i++)
            #pragma unroll
            for (int j = 0; j < 2; j++) {
                f32x4_t t = acc[i][j];
                t = __builtin_amdgcn_mfma_f32_16x16x32_bf16(ah[i], bh[j], t, 0, 0, 0);
                t = __builtin_amdgcn_mfma_f32_16x16x32_bf16(ah[i], bl[j], t, 0, 0, 0);
                t = __builtin_amdgcn_mfma_f32_16x16x32_bf16(al[i], bh[j], t, 0, 0, 0);
                acc[i][j] = t;
            }
        __syncthreads();
    }

    #pragma unroll
    for (int i = 0; i < 4; i++)
        #pragma unroll
        for (int rr = 0; rr < 4; rr++) {
            const int rl = i * 16 + g4 * 4 + rr;
            if (rl >= tcnt) continue;
            const int slot = row0 + rl;
            const int tk = slot_te[slot * 2 + 0];
            const int t = tk >> 1, k = tk & 1;
            const float wgt = slot_w[slot];
            float* y = (k ? y1 : y0) + (long)t * 2048;
            #pragma unroll
            for (int j = 0; j < 2; j++) {
                const int n = n0 + wv * 32 + j * 16 + r16;
                y[n] = wgt * (acc[i][j][rr] + b2[e * 2048 + n]);
            }
        }
}

// ---------------------------------------------------------------------------
// out = x2 + h2 + y0 + y1 + z
// ---------------------------------------------------------------------------
__global__ void final_add_kernel(const float* __restrict__ x2,
                                 const float* __restrict__ h2,
                                 const float* __restrict__ y0,
                                 const float* __restrict__ y1,
                                 const float* __restrict__ z,
                                 float* __restrict__ out, long n)
{
    long i = (long)blockIdx.x * 256 + threadIdx.x;
    if (i >= n) return;
    out[i] = x2[i] + h2[i] + y0[i] + y1[i] + z[i];
}

// ---------------------------------------------------------------------------
extern "C" void kernel_launch(void* const* d_in, const int* in_sizes, int n_in,
                              void* d_out, int out_size, void* d_ws, size_t ws_size,
                              hipStream_t stream)
{
    (void)in_sizes; (void)n_in; (void)out_size; (void)ws_size;

    const float* x          = (const float*)d_in[0];
    const float* attn_nw    = (const float*)d_in[1];
    const float* ffn_nw     = (const float*)d_in[2];
    const float* wq_a_w     = (const float*)d_in[3];
    const float* wq_a_b     = (const float*)d_in[4];
    const float* q_norm_w   = (const float*)d_in[5];
    const float* wq_b_w     = (const float*)d_in[6];
    const float* wq_b_b     = (const float*)d_in[7];
    const float* wkv_a_w    = (const float*)d_in[8];
    const float* wkv_a_b    = (const float*)d_in[9];
    const float* kv_norm_w  = (const float*)d_in[10];
    const float* wkv_b_w    = (const float*)d_in[11];
    const float* wo_w       = (const float*)d_in[12];
    const float* wo_b       = (const float*)d_in[13];
    const float* gate_w     = (const float*)d_in[14];
    const float* gate_b     = (const float*)d_in[15];
    const float* e_w1       = (const float*)d_in[16];
    const float* e_b1       = (const float*)d_in[17];
    const float* e_w2       = (const float*)d_in[18];
    const float* e_b2       = (const float*)d_in[19];
    const float* e_w3       = (const float*)d_in[20];
    const float* e_b3       = (const float*)d_in[21];
    const float* s_w1       = (const float*)d_in[22];
    const float* s_b1       = (const float*)d_in[23];
    const float* s_w2       = (const float*)d_in[24];
    const float* s_b2       = (const float*)d_in[25];
    const float* s_w3       = (const float*)d_in[26];
    const float* s_b3       = (const float*)d_in[27];
    const float* cosb       = (const float*)d_in[28];
    const float* sinb       = (const float*)d_in[29];

    float* ws = (float*)d_ws;
    // Workspace layout (floats)
    float* h    = ws + 0;            // T*2048          (reused later as y0)
    float* qa   = ws + 4194304;      // T*1536
    float* q    = ws + 7340032;      // T*3072          (reused later as y1)
    float* kvf  = ws + 13631488;     // T*576
    float* qabs = ws + 14811136;     // T*H*512 = 16.8M (q_abs, then o, then G)
    float* o2   = ws + 31588352;     // T*2048
    float* x2   = ws + 35782656;     // T*2048
    float* h2   = ws + 39976960;     // T*2048
    float* u1   = ws + 44171264;     // T*2816
    float* u3   = ws + 49938432;     // T*2816          (reused later as z)
    float* wts  = ws + 55705600;     // T*2 floats
    int*   idx  = (int*)(ws + 55709696);     // T*2 ints
    int*   slot_te = (int*)(ws + 55713792);  // 2T*2 ints
    float* slot_w  = ws + 55721984;          // 2T floats
    float* y0 = h;
    float* y1 = q;
    float* z  = u3;

    // Attention scores scratch: [H][S][S] per batch = 16.8M floats, in the
    // dead-until-step-10 o2/x2/h2/u1 region.
    float* scores = o2;

    // MoE scratch inside the (dead after step 10) qabs region:
    float* G = qabs;                              // 2T * MI = 5,767,168 floats
    int* tile_e    = (int*)(qabs + 5767168);
    int* tile_row0 = tile_e + MAX_TILES_;
    int* tile_cnt  = tile_e + 2 * MAX_TILES_;
    int* n_tiles   = tile_e + 3 * MAX_TILES_;

    // 1. h = rms(x, attn_norm_w)
    rms_kernel<<<dim3(T_), 256, 0, stream>>>(x, h, attn_nw, 2048, 2048, 2048);

    // 2. qa = h @ wq_a_w^T + wq_a_b            [T,1536]
    gemm_mfma_kernel<<<dim3(QLR_ / 128, T_ / 128, 1), 256, 0, stream>>>(
        h, 2048, 0, wq_a_w, 2048, 0, 0,
        nullptr, 0, 0, nullptr, 0, 0, 0,
        wq_a_b, 0, nullptr, 0, 0, 0,
        qa, QLR_, 0, QLR_, 2048);

    // 3. qa = rms(qa, q_norm_w) in place
    rms_kernel<<<dim3(T_), 256, 0, stream>>>(qa, qa, q_norm_w, QLR_, QLR_, QLR_);

    // 4. q = qa @ wq_b_w^T + wq_b_b            [T, 3072]
    gemm_mfma_kernel<<<dim3(H_ * QKD_ / 128, T_ / 128, 1), 256, 0, stream>>>(
        qa, QLR_, 0, wq_b_w, QLR_, 0, 0,
        nullptr, 0, 0, nullptr, 0, 0, 0,
        wq_b_b, 0, nullptr, 0, 0, 0,
        q, H_ * QKD_, 0, H_ * QKD_, QLR_);

    // 5. kvf = h @ wkv_a_w^T + wkv_a_b         [T, 576] (N padded to 640)
    gemm_mfma_kernel<<<dim3(5, T_ / 128, 1), 256, 0, stream>>>(
        h, 2048, 0, wkv_a_w, 2048, 0, 0,
        nullptr, 0, 0, nullptr, 0, 0, 0,
        wkv_a_b, 0, nullptr, 0, 0, 0,
        kvf, KVR_ + ROPE_, 0, KVR_ + ROPE_, 2048);

    // 6. RoPE on q_pe (in q) and k_pe (in kvf), in place
    {
        int total_q = T_ * H_ * 32;
        rope_kernel<<<dim3((total_q + 255) / 256), 256, 0, stream>>>(
            q, cosb, sinb, H_, H_ * QKD_, QKD_, NOPE_, total_q);
        int total_k = T_ * 32;
        rope_kernel<<<dim3((total_k + 255) / 256), 256, 0, stream>>>(
            kvf, cosb, sinb, 1, KVR_ + ROPE_, 0, KVR_, total_k);
    }

    // 7. kv_n = rms(kv, kv_norm_w) in place in kvf[:, :512]
    rms_kernel<<<dim3(T_), 256, 0, stream>>>(kvf, kvf, kv_norm_w, KVR_,
                                             KVR_ + ROPE_, KVR_ + ROPE_);

    // 8. q_abs[t,h,:] = q_nope[t,h,:] @ wb1[h]  (W [K=128,N=512] per head)
    gemm_mfma_kernel<<<dim3(KVR_ / 128, T_ / 128, H_), 256, 0, stream>>>(
        q, H_ * QKD_, QKD_,
        wkv_b_w, KVR_, (long)256 * KVR_, 1,
        nullptr, 0, 0, nullptr, 0, 0, 0,
        nullptr, 0, nullptr, 0, 0, 0,
        qabs, H_ * KVR_, KVR_, KVR_, NOPE_);

    // 9. attention as batched GEMMs per batch b (QK fused: K=512 + K2=64)
    for (int b = 0; b < B_; b++) {
        const float* kvb = kvf + (long)b * S_ * (KVR_ + ROPE_);
        gemm_mfma_kernel<<<dim3(S_ / 128, S_ / 128, H_), 256, 0, stream>>>(
            qabs + (long)b * S_ * H_ * KVR_, H_ * KVR_, KVR_,
            kvb, KVR_ + ROPE_, 0, 0,
            q + (long)b * S_ * H_ * QKD_ + NOPE_, H_ * QKD_, QKD_,
            kvb + KVR_, KVR_ + ROPE_, 0, ROPE_,
            nullptr, 0, nullptr, 0, 0, 0,
            scores, S_, (long)S_ * S_, S_, KVR_);
        softmax_kernel<<<dim3(H_ * S_), 256, 0, stream>>>(scores);
        gemm_mfma_kernel<<<dim3(KVR_ / 128, S_ / 128, H_), 256, 0, stream>>>(
            scores, S_, (long)S_ * S_,
            kvb, KVR_ + ROPE_, 0, 1,
            nullptr, 0, 0, nullptr, 0, 0, 0,
            nullptr, 0, nullptr, 0, 0, 0,
            qabs + (long)b * S_ * H_ * KVR_, H_ * KVR_, KVR_, KVR_, S_);
    }

    // 10. o2[t,h,:] = o[t,h,:] @ wb2[h]^T
    gemm_mfma_kernel<<<dim3(VD_ / 128, T_ / 128, H_), 256, 0, stream>>>(
        qabs, H_ * KVR_, KVR_,
        wkv_b_w + (long)NOPE_ * KVR_, KVR_, (long)256 * KVR_, 0,
        nullptr, 0, 0, nullptr, 0, 0, 0,
        nullptr, 0, nullptr, 0, 0, 0,
        o2, H_ * VD_, VD_, VD_, KVR_);

    // 11. x2 = x + o2 @ wo_w^T + wo_b
    gemm_mfma_kernel<<<dim3(D_ / 128, T_ / 128, 1), 256, 0, stream>>>(
        o2, 2048, 0, wo_w, 2048, 0, 0,
        nullptr, 0, 0, nullptr, 0, 0, 0,
        wo_b, 0, x, 2048, 0, 1,
        x2, 2048, 0, D_, 2048);

    // 12. h2 = rms(x2, ffn_norm_w)
    rms_kernel<<<dim3(T_), 256, 0, stream>>>(x2, h2, ffn_nw, 2048, 2048, 2048);

    // 13. gate -> top2
    gate_kernel<<<dim3(T_), 256, 0, stream>>>(h2, gate_w, gate_b, idx, wts);

    // 14. route
    route_kernel<<<dim3(1), 256, 0, stream>>>(idx, wts, slot_te, slot_w,
                                              tile_e, tile_row0, tile_cnt, n_tiles);

    // 15. MoE batched per-expert MFMA GEMMs
    moe_mlp13_kernel<<<dim3(MI_ / 128, MAX_TILES_), 256, 0, stream>>>(
        h2, slot_te, tile_e, tile_row0, tile_cnt, n_tiles,
        e_w1, e_b1, e_w3, e_b3, G);
    moe_mlp2_kernel<<<dim3(D_ / 128, MAX_TILES_), 256, 0, stream>>>(
        G, slot_te, slot_w, tile_e, tile_row0, tile_cnt, n_tiles,
        e_w2, e_b2, y0, y1);

    // 16. shared MLP (silu fused into the s_w3 GEMM epilogue, res_mode=2)
    gemm_mfma_kernel<<<dim3(SMI_ / 128, T_ / 128, 1), 256, 0, stream>>>(
        h2, 2048, 0, s_w1, 2048, 0, 0,
        nullptr, 0, 0, nullptr, 0, 0, 0,
        s_b1, 0, nullptr, 0, 0, 0,
        u1, SMI_, 0, SMI_, 2048);
    gemm_mfma_kernel<<<dim3(SMI_ / 128, T_ / 128, 1), 256, 0, stream>>>(
        h2, 2048, 0, s_w3, 2048, 0, 0,
        nullptr, 0, 0, nullptr, 0, 0, 0,
        s_b3, 0, u1, SMI_, 0, 2,
        u1, SMI_, 0, SMI_, 2048);
    gemm_mfma_kernel<<<dim3(D_ / 128, T_ / 128, 1), 256, 0, stream>>>(
        u1, SMI_, 0, s_w2, SMI_, 0, 0,
        nullptr, 0, 0, nullptr, 0, 0, 0,
        s_b2, 0, nullptr, 0, 0, 0,
        z, D_, 0, D_, SMI_);

    // 17. out = x2 + h2 + y0 + y1 + z
    {
        long n = (long)T_ * D_;
        final_add_kernel<<<dim3((unsigned)((n + 255) / 256)), 256, 0, stream>>>(
            x2, h2, y0, y1, z, (float*)d_out, n);
    }
}

// Round 5
// 2210.422 us; speedup vs baseline: 19.7480x; 1.2141x over previous
//
#include <hip/hip_runtime.h>
#include <math.h>

// Problem constants
constexpr int B_ = 2, S_ = 1024, D_ = 2048, H_ = 16;
constexpr int NOPE_ = 128, ROPE_ = 64, VD_ = 128, KVR_ = 512, QLR_ = 1536;
constexpr int NE_ = 16, MI_ = 1408, SMI_ = 2816;
constexpr int QKD_ = NOPE_ + ROPE_;            // 192
constexpr int T_ = B_ * S_;                    // 2048
constexpr float SCALE_ = 0.07216878364870322f; // 192^-0.5
constexpr float EPS_ = 1e-3f;
constexpr int MAX_TILES_ = 80;

typedef unsigned short u16;
typedef __attribute__((ext_vector_type(8))) short  bf16x8_t;
typedef __attribute__((ext_vector_type(4))) float  f32x4_t;
typedef __attribute__((ext_vector_type(4))) u16 us4_t;

// Plane-pair element counts (lo plane = base + E ushorts)
constexpr long E_H = 4194304, E_QA = 3145728, E_Q = 6291456, E_KVF = 1179648;
constexpr long E_KVFT = 1048576, E_QABS = 16777216, E_SCORES = 16777216;
constexpr long E_O2 = 4194304, E_H2 = 4194304, E_U1 = 5767168, E_G = 5767168;
constexpr long E_WQA = 3145728, E_WQB = 4718592, E_WKVA = 1310720;
constexpr long E_WKVB = 2097152, E_WKVB1T = 1048576, E_WO = 4194304, E_SW = 5767168;

// fp32 -> bf16 hi + lo split (truncation; lo captures hi's error).
__device__ __forceinline__ void split_bf(float v, u16& h, u16& l)
{
    unsigned int u = __float_as_uint(v);
    h = (u16)(u >> 16);
    float lo = v - __uint_as_float(u & 0xFFFF0000u);
    l = (u16)(__float_as_uint(lo) >> 16);
}

__device__ __forceinline__ void split4(const float4& v, us4_t& h, us4_t& l)
{
    split_bf(v.x, ((u16*)&h)[0], ((u16*)&l)[0]);
    split_bf(v.y, ((u16*)&h)[1], ((u16*)&l)[1]);
    split_bf(v.z, ((u16*)&h)[2], ((u16*)&l)[2]);
    split_bf(v.w, ((u16*)&h)[3], ((u16*)&l)[3]);
}

// ---------------------------------------------------------------------------
// Stage a 128-row x 64-bf16 tile (16 KB) of one plane into LDS via
// global_load_lds (linear dest, inverse-XOR-swizzled source). g points at
// tile row 0 of the plane; ld in elems; kt = k offset (elems).
// ---------------------------------------------------------------------------
__device__ __forceinline__ void stage_one(
    const u16* __restrict__ g, int ld, int kt, u16* lds, int lane, int wv)
{
    #pragma unroll
    for (int it = 0; it < 4; it++) {
        const int issue = wv * 4 + it;
        const int row = issue * 8 + (lane >> 3);
        const int colb = ((lane & 7) << 4) ^ ((row & 7) << 4);
        const u16* gp = g + (long)row * ld + kt + (colb >> 1);
        u16* lp = lds + issue * 512;   // wave-uniform; HW adds lane*16B
        __builtin_amdgcn_global_load_lds(
            (const __attribute__((address_space(1))) unsigned int*)gp,
            (__attribute__((address_space(3))) unsigned int*)lp, 16, 0, 0);
    }
}

// Read a bf16x8 fragment from the swizzled [128][64] bf16 LDS tile.
__device__ __forceinline__ bf16x8_t fragld(const u16* lds, int row, int slot)
{
    const int byte = (row << 7) + ((slot << 4) ^ ((row & 7) << 4));
    return *(const bf16x8_t*)((const char*)lds + byte);
}

// ---------------------------------------------------------------------------
// MFMA bf16x3 GEMM on plane-pair operands. C = A@B^T (+A2@B2^T) + bias +res.
// 128x128 tile, BK=64, 4 waves (2x2) each 64x64. M%128==0, K%64==0, K2%64==0.
// All operands stored as bf16 hi/lo planes (lo at +plo ushorts), row-major
// [rows][ld]. B tiles are [n][k]. Output: Cf (fp32) or Cp (planes).
// res_mode: 0 none, 1 add, 2 C = silu(res) * (acc+bias).
// ---------------------------------------------------------------------------
__global__ __launch_bounds__(256) void gemm_bf_kernel(
    const u16* __restrict__ A, long ploA, int lda, long strideA,
    const u16* __restrict__ B, long ploB, int ldb, long strideB,
    const u16* __restrict__ A2, long ploA2, int lda2, long strideA2,
    const u16* __restrict__ B2, long ploB2, int ldb2, long strideB2, int K2,
    const float* __restrict__ bias,
    const float* __restrict__ res, int ldr, long strideRes, int res_mode,
    float* __restrict__ Cf, u16* __restrict__ Cp, long ploC,
    int ldc, long strideC,
    int Nlim, int K)
{
    const int bz = blockIdx.z;
    A += bz * strideA; B += bz * strideB;
    if (A2)  A2 += bz * strideA2;
    if (B2)  B2 += bz * strideB2;
    if (res) res += bz * strideRes;
    if (Cf)  Cf += bz * strideC;
    if (Cp)  Cp += bz * strideC;

    __shared__ __align__(16) u16 Ah[128 * 64], Al[128 * 64];
    __shared__ __align__(16) u16 Bh[128 * 64], Bl[128 * 64];

    const int m0 = blockIdx.y * 128, n0 = blockIdx.x * 128;
    const int tid = threadIdx.x, lane = tid & 63, wv = tid >> 6;
    const int wm = (wv >> 1) * 64, wn = (wv & 1) * 64;
    const int r16 = lane & 15, g4 = lane >> 4;

    f32x4_t acc[4][4];
    #pragma unroll
    for (int i = 0; i < 4; i++)
        #pragma unroll
        for (int j = 0; j < 4; j++) acc[i][j] = (f32x4_t){0.f, 0.f, 0.f, 0.f};

    auto do_tile = [&]() {
        #pragma unroll
        for (int ks = 0; ks < 2; ks++) {
            const int slot = ks * 4 + g4;
            bf16x8_t ah[4], al[4], bh[4], bl[4];
            #pragma unroll
            for (int i = 0; i < 4; i++) {
                ah[i] = fragld(Ah, wm + i * 16 + r16, slot);
                al[i] = fragld(Al, wm + i * 16 + r16, slot);
                bh[i] = fragld(Bh, wn + i * 16 + r16, slot);
                bl[i] = fragld(Bl, wn + i * 16 + r16, slot);
            }
            #pragma unroll
            for (int i = 0; i < 4; i++)
                #pragma unroll
                for (int j = 0; j < 4; j++) {
                    f32x4_t t = acc[i][j];
                    t = __builtin_amdgcn_mfma_f32_16x16x32_bf16(ah[i], bh[j], t, 0, 0, 0);
                    t = __builtin_amdgcn_mfma_f32_16x16x32_bf16(ah[i], bl[j], t, 0, 0, 0);
                    t = __builtin_amdgcn_mfma_f32_16x16x32_bf16(al[i], bh[j], t, 0, 0, 0);
                    acc[i][j] = t;
                }
        }
    };

    const u16* Ab = A + (long)m0 * lda;
    const u16* Bb = B + (long)n0 * ldb;
    for (int kt = 0; kt < K; kt += 64) {
        stage_one(Ab,        lda, kt, Ah, lane, wv);
        stage_one(Ab + ploA, lda, kt, Al, lane, wv);
        stage_one(Bb,        ldb, kt, Bh, lane, wv);
        stage_one(Bb + ploB, ldb, kt, Bl, lane, wv);
        __syncthreads();
        do_tile();
        __syncthreads();
    }
    if (K2 > 0) {
        const u16* A2b = A2 + (long)m0 * lda2;
        const u16* B2b = B2 + (long)n0 * ldb2;
        for (int kt = 0; kt < K2; kt += 64) {
            stage_one(A2b,         lda2, kt, Ah, lane, wv);
            stage_one(A2b + ploA2, lda2, kt, Al, lane, wv);
            stage_one(B2b,         ldb2, kt, Bh, lane, wv);
            stage_one(B2b + ploB2, ldb2, kt, Bl, lane, wv);
            __syncthreads();
            do_tile();
            __syncthreads();
        }
    }

    #pragma unroll
    for (int i = 0; i < 4; i++)
        #pragma unroll
        for (int rr = 0; rr < 4; rr++) {
            const int m = m0 + wm + i * 16 + g4 * 4 + rr;
            #pragma unroll
            for (int j = 0; j < 4; j++) {
                const int n = n0 + wn + j * 16 + r16;
                if (n >= Nlim) continue;
                float v = acc[i][j][rr];
                if (bias) v += bias[n];
                if (res_mode == 1) {
                    v += res[(long)m * ldr + n];
                } else if (res_mode == 2) {
                    float r = res[(long)m * ldr + n];
                    v = (r / (1.f + expf(-r))) * v;
                }
                if (Cf) {
                    Cf[(long)m * ldc + n] = v;
                } else {
                    u16 hh, ll; split_bf(v, hh, ll);
                    Cp[(long)m * ldc + n] = hh;
                    Cp[ploC + (long)m * ldc + n] = ll;
                }
            }
        }
}

// ---------------------------------------------------------------------------
// Converters
// ---------------------------------------------------------------------------
__global__ void conv_pl_kernel(const float* __restrict__ src,
                               u16* __restrict__ dst, long plo, long n)
{
    long i = ((long)blockIdx.x * 256 + threadIdx.x) * 4;
    if (i >= n) return;
    float4 v = *(const float4*)(src + i);
    us4_t h, l; split4(v, h, l);
    *(us4_t*)(dst + i) = h;
    *(us4_t*)(dst + plo + i) = l;
}

// out[h][n<512][k<128] = wkv_b[(h*256+k)*512 + n]
__global__ __launch_bounds__(256) void conv_wkvb1T_kernel(
    const float* __restrict__ src, u16* __restrict__ dst, long plo)
{
    __shared__ float t[32][33];
    const int h = blockIdx.z, n0 = blockIdx.y * 32, k0 = blockIdx.x * 32;
    const int tx = threadIdx.x & 31, ty = threadIdx.x >> 5;
    #pragma unroll
    for (int i = 0; i < 4; i++) {
        int k = k0 + ty + i * 8;
        t[ty + i * 8][tx] = src[((long)(h * 256 + k)) * 512 + (n0 + tx)];
    }
    __syncthreads();
    #pragma unroll
    for (int i = 0; i < 4; i++) {
        int n = n0 + ty + i * 8;
        float v = t[tx][ty + i * 8];
        u16 hh, ll; split_bf(v, hh, ll);
        long o = ((long)h * 512 + n) * 128 + (k0 + tx);
        dst[o] = hh; dst[plo + o] = ll;
    }
}

// out[b][c<512][t<1024] = kvf[(b*1024+t)*576 + c]
__global__ __launch_bounds__(256) void conv_kvfT_kernel(
    const float* __restrict__ src, u16* __restrict__ dst, long plo)
{
    __shared__ float tl[32][33];
    const int b = blockIdx.z, c0 = blockIdx.y * 32, t0 = blockIdx.x * 32;
    const int tx = threadIdx.x & 31, ty = threadIdx.x >> 5;
    #pragma unroll
    for (int i = 0; i < 4; i++) {
        int t = t0 + ty + i * 8;
        tl[ty + i * 8][tx] = src[((long)(b * 1024 + t)) * 576 + (c0 + tx)];
    }
    __syncthreads();
    #pragma unroll
    for (int i = 0; i < 4; i++) {
        int c = c0 + ty + i * 8;
        float v = tl[tx][ty + i * 8];
        u16 hh, ll; split_bf(v, hh, ll);
        long o = ((long)b * 512 + c) * 1024 + (t0 + tx);
        dst[o] = hh; dst[plo + o] = ll;
    }
}

// ---------------------------------------------------------------------------
// RMSNorm: fp32 in -> planes out (+ optional fp32 out)
// ---------------------------------------------------------------------------
__global__ __launch_bounds__(256) void rms_pl_kernel(
    const float* __restrict__ in, int in_stride,
    u16* __restrict__ outp, long plo, int out_stride,
    const float* __restrict__ w, int N, float* __restrict__ outf)
{
    const int row = blockIdx.x;
    const float* x = in + (long)row * in_stride;
    __shared__ float red[256];
    const int tid = threadIdx.x;
    float s = 0.f;
    for (int i = tid; i < N; i += 256) { float v = x[i]; s += v * v; }
    red[tid] = s; __syncthreads();
    for (int st = 128; st > 0; st >>= 1) {
        if (tid < st) red[tid] += red[tid + st];
        __syncthreads();
    }
    const float scale = rsqrtf(red[0] / (float)N + EPS_);
    for (int i = tid; i < N; i += 256) {
        float v = w[i] * x[i] * scale;
        u16 hh, ll; split_bf(v, hh, ll);
        outp[(long)row * out_stride + i] = hh;
        outp[plo + (long)row * out_stride + i] = ll;
        if (outf) outf[(long)row * out_stride + i] = v;
    }
}

// fp32 in-place RMSNorm (kvf)
__global__ __launch_bounds__(256) void rms_kernel(
    const float* __restrict__ in, float* __restrict__ out,
    const float* __restrict__ w, int N, int in_stride, int out_stride)
{
    const int row = blockIdx.x;
    const float* x = in + (long)row * in_stride;
    float* y = out + (long)row * out_stride;
    __shared__ float red[256];
    const int tid = threadIdx.x;
    float s = 0.f;
    for (int i = tid; i < N; i += 256) { float v = x[i]; s += v * v; }
    red[tid] = s; __syncthreads();
    for (int st = 128; st > 0; st >>= 1) {
        if (tid < st) red[tid] += red[tid + st];
        __syncthreads();
    }
    const float scale = rsqrtf(red[0] / (float)N + EPS_);
    for (int i = tid; i < N; i += 256) y[i] = w[i] * x[i] * scale;
}

// ---------------------------------------------------------------------------
// Interleaved RoPE, in place (fp32).
// ---------------------------------------------------------------------------
__global__ void rope_kernel(float* __restrict__ p,
                            const float* __restrict__ cosb,
                            const float* __restrict__ sinb,
                            int nheads, int row_stride, int head_stride,
                            int off, int total)
{
    int i = blockIdx.x * 256 + threadIdx.x;
    if (i >= total) return;
    int pair = i & 31;
    int rem = i >> 5;
    int h = rem % nheads;
    int t = rem / nheads;
    int s = t % S_;
    float c = cosb[s * 32 + pair], sn = sinb[s * 32 + pair];
    float* base = p + (long)t * row_stride + (long)h * head_stride + off + pair * 2;
    float x0 = base[0], x1 = base[1];
    base[0] = x0 * c - x1 * sn;
    base[1] = x0 * sn + x1 * c;
}

// ---------------------------------------------------------------------------
// Row softmax (1024 wide), scale folded in; fp32 in -> planes out.
// ---------------------------------------------------------------------------
__global__ __launch_bounds__(256) void softmax_pl_kernel(
    const float* __restrict__ in, u16* __restrict__ outp, long plo)
{
    const long row = blockIdx.x;
    const float* src = in + row * 1024;
    const int tid = threadIdx.x;
    __shared__ float red[256];

    float4 v = ((const float4*)src)[tid];
    v.x *= SCALE_; v.y *= SCALE_; v.z *= SCALE_; v.w *= SCALE_;

    float m = fmaxf(fmaxf(v.x, v.y), fmaxf(v.z, v.w));
    red[tid] = m; __syncthreads();
    for (int st = 128; st > 0; st >>= 1) {
        if (tid < st) red[tid] = fmaxf(red[tid], red[tid + st]);
        __syncthreads();
    }
    m = red[0];
    __syncthreads();

    v.x = __expf(v.x - m); v.y = __expf(v.y - m);
    v.z = __expf(v.z - m); v.w = __expf(v.w - m);
    float s = v.x + v.y + v.z + v.w;
    red[tid] = s; __syncthreads();
    for (int st = 128; st > 0; st >>= 1) {
        if (tid < st) red[tid] += red[tid + st];
        __syncthreads();
    }
    const float inv = 1.f / red[0];
    v.x *= inv; v.y *= inv; v.z *= inv; v.w *= inv;

    us4_t h, l; split4(v, h, l);
    *(us4_t*)(outp + row * 1024 + tid * 4) = h;
    *(us4_t*)(outp + plo + row * 1024 + tid * 4) = l;
}

// ---------------------------------------------------------------------------
// Gate + route (unchanged)
// ---------------------------------------------------------------------------
__global__ __launch_bounds__(256) void gate_kernel(
    const float* __restrict__ h2, const float* __restrict__ gw,
    const float* __restrict__ gb, int* __restrict__ idx,
    float* __restrict__ wts)
{
    const int t = blockIdx.x;
    __shared__ float red[256];
    __shared__ float logits[16];
    const int tid = threadIdx.x;
    const int e = tid >> 4, lane = tid & 15;
    const float* x = h2 + (long)t * 2048;
    float s = 0.f;
    for (int i = lane; i < 2048; i += 16) s += x[i] * gw[e * 2048 + i];
    red[tid] = s; __syncthreads();
    for (int st = 8; st > 0; st >>= 1) {
        if (lane < st) red[tid] += red[tid + st];
        __syncthreads();
    }
    if (lane == 0) logits[e] = red[e * 16] + gb[e];
    __syncthreads();
    if (tid == 0) {
        float m = logits[0];
        for (int j = 1; j < 16; j++) m = fmaxf(m, logits[j]);
        float pr[16]; float sum = 0.f;
        for (int j = 0; j < 16; j++) { pr[j] = expf(logits[j] - m); sum += pr[j]; }
        float inv = 1.f / sum;
        for (int j = 0; j < 16; j++) pr[j] *= inv;
        int i1 = 0; float v1 = -1e30f;
        for (int j = 0; j < 16; j++) { float v = pr[j] + gb[j]; if (v > v1) { v1 = v; i1 = j; } }
        int i2 = 0; float v2 = -1e30f;
        for (int j = 0; j < 16; j++) { if (j == i1) continue; float v = pr[j] + gb[j]; if (v > v2) { v2 = v; i2 = j; } }
        idx[t * 2 + 0] = i1; idx[t * 2 + 1] = i2;
        wts[t * 2 + 0] = pr[i1]; wts[t * 2 + 1] = pr[i2];
    }
}

__global__ __launch_bounds__(256) void route_kernel(
    const int* __restrict__ idx, const float* __restrict__ wts,
    int* __restrict__ slot_te, float* __restrict__ slot_w,
    int* __restrict__ tile_e, int* __restrict__ tile_row0,
    int* __restrict__ tile_cnt, int* __restrict__ n_tiles)
{
    __shared__ int counts[16], offs[16], cursor[16];
    const int tid = threadIdx.x;
    if (tid < 16) { counts[tid] = 0; cursor[tid] = 0; }
    __syncthreads();
    for (int a = tid; a < 2 * T_; a += 256) atomicAdd(&counts[idx[a]], 1);
    __syncthreads();
    if (tid == 0) {
        int o = 0;
        for (int e = 0; e < 16; e++) { offs[e] = o; o += counts[e]; }
        int nt = 0;
        for (int e = 0; e < 16; e++) {
            for (int r0 = 0; r0 < counts[e]; r0 += 64) {
                tile_e[nt] = e;
                tile_row0[nt] = offs[e] + r0;
                int c = counts[e] - r0;
                tile_cnt[nt] = c < 64 ? c : 64;
                nt++;
            }
        }
        *n_tiles = nt;
    }
    __syncthreads();
    for (int a = tid; a < 2 * T_; a += 256) {
        int e = idx[a];
        int pos = offs[e] + atomicAdd(&cursor[e], 1);
        int t = a >> 1, k = a & 1;
        slot_te[pos * 2 + 0] = (t << 1) | k;
        slot_te[pos * 2 + 1] = e;
        slot_w[pos] = wts[a];
    }
}

// ---------------------------------------------------------------------------
// MoE stage 1: A from h2 planes; W1/W3 fp32-split in kernel (expert weights
// are read only ~2-4x, prepass is net-negative). G written as planes.
// ---------------------------------------------------------------------------
__global__ __launch_bounds__(256) void moe_mlp13_kernel(
    const u16* __restrict__ h2p, long ploH2,
    const int* __restrict__ slot_te,
    const int* __restrict__ tile_e, const int* __restrict__ tile_row0,
    const int* __restrict__ tile_cnt, const int* __restrict__ n_tiles,
    const float* __restrict__ w1, const float* __restrict__ b1,
    const float* __restrict__ w3, const float* __restrict__ b3,
    u16* __restrict__ Gp, long ploG)
{
    const int tile = blockIdx.y;
    if (tile >= *n_tiles) return;
    const int e    = tile_e[tile];
    const int row0 = tile_row0[tile];
    const int tcnt = tile_cnt[tile];
    const int n0   = blockIdx.x * 128;

    __shared__ u16 Ah[64][40],  Al[64][40];
    __shared__ u16 B1h[128][40], B1l[128][40];
    __shared__ u16 B3h[128][40], B3l[128][40];
    __shared__ int tok[64];

    const int tid  = threadIdx.x;
    const int lane = tid & 63;
    const int wv   = tid >> 6;
    const int r16 = lane & 15, g4 = lane >> 4;

    if (tid < 64) {
        int r = tid < tcnt ? tid : tcnt - 1;
        tok[tid] = slot_te[(row0 + r) * 2 + 0] >> 1;
    }
    __syncthreads();

    const float* W1 = w1 + (long)e * MI_ * 2048;
    const float* W3 = w3 + (long)e * MI_ * 2048;

    f32x4_t acc1[4][2], acc3[4][2];
    #pragma unroll
    for (int i = 0; i < 4; i++)
        #pragma unroll
        for (int j = 0; j < 2; j++) {
            acc1[i][j] = (f32x4_t){0.f, 0.f, 0.f, 0.f};
            acc3[i][j] = (f32x4_t){0.f, 0.f, 0.f, 0.f};
        }

    const int sr   = tid >> 3;
    const int scol = (tid & 7) * 4;

    for (int kt = 0; kt < 2048; kt += 32) {
        #pragma unroll
        for (int rr = 0; rr < 64; rr += 32) {
            long o = (long)tok[rr + sr] * 2048 + (kt + scol);
            *(us4_t*)&Ah[rr + sr][scol] = *(const us4_t*)(h2p + o);
            *(us4_t*)&Al[rr + sr][scol] = *(const us4_t*)(h2p + ploH2 + o);
        }
        #pragma unroll
        for (int rr = 0; rr < 128; rr += 32) {
            const long woff = (long)(n0 + rr + sr) * 2048 + (kt + scol);
            {
                const float4 v = *(const float4*)(W1 + woff);
                us4_t h, l; split4(v, h, l);
                *(us4_t*)&B1h[rr + sr][scol] = h;
                *(us4_t*)&B1l[rr + sr][scol] = l;
            }
            {
                const float4 v = *(const float4*)(W3 + woff);
                us4_t h, l; split4(v, h, l);
                *(us4_t*)&B3h[rr + sr][scol] = h;
                *(us4_t*)&B3l[rr + sr][scol] = l;
            }
        }
        __syncthreads();

        bf16x8_t ah[4], al[4], b1h[2], b1l[2], b3h[2], b3l[2];
        #pragma unroll
        for (int i = 0; i < 4; i++) {
            ah[i] = *(const bf16x8_t*)&Ah[i * 16 + r16][g4 * 8];
            al[i] = *(const bf16x8_t*)&Al[i * 16 + r16][g4 * 8];
        }
        #pragma unroll
        for (int j = 0; j < 2; j++) {
            const int cn = wv * 32 + j * 16 + r16;
            b1h[j] = *(const bf16x8_t*)&B1h[cn][g4 * 8];
            b1l[j] = *(const bf16x8_t*)&B1l[cn][g4 * 8];
            b3h[j] = *(const bf16x8_t*)&B3h[cn][g4 * 8];
            b3l[j] = *(const bf16x8_t*)&B3l[cn][g4 * 8];
        }
        #pragma unroll
        for (int i = 0; i < 4; i++)
            #pragma unroll
            for (int j = 0; j < 2; j++) {
                f32x4_t t = acc1[i][j];
                t = __builtin_amdgcn_mfma_f32_16x16x32_bf16(ah[i], b1h[j], t, 0, 0, 0);
                t = __builtin_amdgcn_mfma_f32_16x16x32_bf16(ah[i], b1l[j], t, 0, 0, 0);
                t = __builtin_amdgcn_mfma_f32_16x16x32_bf16(al[i], b1h[j], t, 0, 0, 0);
                acc1[i][j] = t;
                f32x4_t u = acc3[i][j];
                u = __builtin_amdgcn_mfma_f32_16x16x32_bf16(ah[i], b3h[j], u, 0, 0, 0);
                u = __builtin_amdgcn_mfma_f32_16x16x32_bf16(ah[i], b3l[j], u, 0, 0, 0);
                u = __builtin_amdgcn_mfma_f32_16x16x32_bf16(al[i], b3h[j], u, 0, 0, 0);
                acc3[i][j] = u;
            }
        __syncthreads();
    }

    #pragma unroll
    for (int i = 0; i < 4; i++)
        #pragma unroll
        for (int rr = 0; rr < 4; rr++) {
            const int rl = i * 16 + g4 * 4 + rr;
            if (rl >= tcnt) continue;
            const long grow = (long)(row0 + rl) * MI_;
            #pragma unroll
            for (int j = 0; j < 2; j++) {
                const int n = n0 + wv * 32 + j * 16 + r16;
                float a = acc1[i][j][rr] + b1[e * MI_ + n];
                float b = acc3[i][j][rr] + b3[e * MI_ + n];
                float g = (a / (1.f + expf(-a))) * b;
                u16 hh, ll; split_bf(g, hh, ll);
                Gp[grow + n] = hh;
                Gp[ploG + grow + n] = ll;
            }
        }
}

// ---------------------------------------------------------------------------
// MoE stage 2: A from G planes; W2 fp32-split in kernel.
// ---------------------------------------------------------------------------
__global__ __launch_bounds__(256) void moe_mlp2_kernel(
    const u16* __restrict__ Gp, long ploG,
    const int* __restrict__ slot_te, const float* __restrict__ slot_w,
    const int* __restrict__ tile_e, const int* __restrict__ tile_row0,
    const int* __restrict__ tile_cnt, const int* __restrict__ n_tiles,
    const float* __restrict__ w2, const float* __restrict__ b2,
    float* __restrict__ y0, float* __restrict__ y1)
{
    const int tile = blockIdx.y;
    if (tile >= *n_tiles) return;
    const int e    = tile_e[tile];
    const int row0 = tile_row0[tile];
    const int tcnt = tile_cnt[tile];
    const int n0   = blockIdx.x * 128;

    __shared__ u16 Ah[64][40], Al[64][40];
    __shared__ u16 Bh[128][40], Bl[128][40];
    __shared__ int rsrc[64];

    const int tid  = threadIdx.x;
    const int lane = tid & 63;
    const int wv   = tid >> 6;
    const int r16 = lane & 15, g4 = lane >> 4;

    if (tid < 64) {
        int r = tid < tcnt ? tid : tcnt - 1;
        rsrc[tid] = row0 + r;
    }
    __syncthreads();

    const float* W2 = w2 + (long)e * 2048 * MI_;

    f32x4_t acc[4][2];
    #pragma unroll
    for (int i = 0; i < 4; i++)
        #pragma unroll
        for (int j = 0; j < 2; j++) acc[i][j] = (f32x4_t){0.f, 0.f, 0.f, 0.f};

    const int sr   = tid >> 3;
    const int scol = (tid & 7) * 4;

    for (int kt = 0; kt < MI_; kt += 32) {
        #pragma unroll
        for (int rr = 0; rr < 64; rr += 32) {
            long o = (long)rsrc[rr + sr] * MI_ + (kt + scol);
            *(us4_t*)&Ah[rr + sr][scol] = *(const us4_t*)(Gp + o);
            *(us4_t*)&Al[rr + sr][scol] = *(const us4_t*)(Gp + ploG + o);
        }
        #pragma unroll
        for (int rr = 0; rr < 128; rr += 32) {
            const float4 v = *(const float4*)(W2 + (long)(n0 + rr + sr) * MI_ + (kt + scol));
            us4_t h, l; split4(v, h, l);
            *(us4_t*)&Bh[rr + sr][scol] = h;
            *(us4_t*)&Bl[rr + sr][scol] = l;
        }
        __syncthreads();

        bf16x8_t ah[4], al[4], bh[2], bl[2];
        #pragma unroll
        for (int i = 0; i < 4; i++) {
            ah[i] = *(const bf16x8_t*)&Ah[i * 16 + r16][g4 * 8];
            al[i] = *(const bf16x8_t*)&Al[i * 16 + r16][g4 * 8];
        }
        #pragma unroll
        for (int j = 0; j < 2; j++) {
            const int cn = wv * 32 + j * 16 + r16;
            bh[j] = *(const bf16x8_t*)&Bh[cn][g4 * 8];
            bl[j] = *(const bf16x8_t*)&Bl[cn][g4 * 8];
        }
        #pragma unroll
        for (int i = 0; i < 4; i++)
            #pragma unroll
            for (int j = 0; j < 2; j++) {
                f32x4_t t = acc[i][j];
                t = __builtin_amdgcn_mfma_f32_16x16x32_bf16(ah[i], bh[j], t, 0, 0, 0);
                t = __builtin_amdgcn_mfma_f32_16x16x32_bf16(ah[i], bl[j], t, 0, 0, 0);
                t = __builtin_amdgcn_mfma_f32_16x16x32_bf16(al[i], bh[j], t, 0, 0, 0);
                acc[i][j] = t;
            }
        __syncthreads();
    }

    #pragma unroll
    for (int i = 0; i < 4; i++)
        #pragma unroll
        for (int rr = 0; rr < 4; rr++) {
            const int rl = i * 16 + g4 * 4 + rr;
            if (rl >= tcnt) continue;
            const int slot = row0 + rl;
            const int tk = slot_te[slot * 2 + 0];
            const int t = tk >> 1, k = tk & 1;
            const float wgt = slot_w[slot];
            float* y = (k ? y1 : y0) + (long)t * 2048;
            #pragma unroll
            for (int j = 0; j < 2; j++) {
                const int n = n0 + wv * 32 + j * 16 + r16;
                y[n] = wgt * (acc[i][j][rr] + b2[e * 2048 + n]);
            }
        }
}

// ---------------------------------------------------------------------------
__global__ void final_add_kernel(const float* __restrict__ x2,
                                 const float* __restrict__ h2,
                                 const float* __restrict__ y0,
                                 const float* __restrict__ y1,
                                 const float* __restrict__ z,
                                 float* __restrict__ out, long n)
{
    long i = (long)blockIdx.x * 256 + threadIdx.x;
    if (i >= n) return;
    out[i] = x2[i] + h2[i] + y0[i] + y1[i] + z[i];
}

// ---------------------------------------------------------------------------
extern "C" void kernel_launch(void* const* d_in, const int* in_sizes, int n_in,
                              void* d_out, int out_size, void* d_ws, size_t ws_size,
                              hipStream_t stream)
{
    (void)in_sizes; (void)n_in; (void)out_size; (void)ws_size;

    const float* x          = (const float*)d_in[0];
    const float* attn_nw    = (const float*)d_in[1];
    const float* ffn_nw     = (const float*)d_in[2];
    const float* wq_a_w     = (const float*)d_in[3];
    const float* wq_a_b     = (const float*)d_in[4];
    const float* q_norm_w   = (const float*)d_in[5];
    const float* wq_b_w     = (const float*)d_in[6];
    const float* wq_b_b     = (const float*)d_in[7];
    const float* wkv_a_w    = (const float*)d_in[8];
    const float* wkv_a_b    = (const float*)d_in[9];
    const float* kv_norm_w  = (const float*)d_in[10];
    const float* wkv_b_w    = (const float*)d_in[11];
    const float* wo_w       = (const float*)d_in[12];
    const float* wo_b       = (const float*)d_in[13];
    const float* gate_w     = (const float*)d_in[14];
    const float* gate_b     = (const float*)d_in[15];
    const float* e_w1       = (const float*)d_in[16];
    const float* e_b1       = (const float*)d_in[17];
    const float* e_w2       = (const float*)d_in[18];
    const float* e_b2       = (const float*)d_in[19];
    const float* e_w3       = (const float*)d_in[20];
    const float* e_b3       = (const float*)d_in[21];
    const float* s_w1       = (const float*)d_in[22];
    const float* s_b1       = (const float*)d_in[23];
    const float* s_w2       = (const float*)d_in[24];
    const float* s_b2       = (const float*)d_in[25];
    const float* s_w3       = (const float*)d_in[26];
    const float* s_b3       = (const float*)d_in[27];
    const float* cosb       = (const float*)d_in[28];
    const float* sinb       = (const float*)d_in[29];

    float* ws = (float*)d_ws;

    // fp32 buffers (with overlays: scores_f32 over u1/y region pre-FFN;
    // G planes over qa_f32/q_f32 post-attention)
    float* qa_f   = ws + 0;          // 3,145,728
    float* q_f    = ws + 3145728;    // 6,291,456
    float* kvf_f  = ws + 9437184;    // 1,179,648
    float* x2     = ws + 10616832;   // 4,194,304
    float* h2_f   = ws + 14811136;   // 4,194,304
    float* u1_f   = ws + 19005440;   // 5,767,168
    float* y0     = ws + 24772608;   // 4,194,304
    float* y1     = ws + 28966912;   // 4,194,304
    float* z      = ws + 33161216;   // 4,194,304
    float* wts    = ws + 37355520;   // 4096
    int*   idx    = (int*)(ws + 37359616);
    int*   slot_te= (int*)(ws + 37363712);
    float* slot_w = ws + 37371904;
    int*   tile_e = (int*)(ws + 37376000);
    int*   tile_row0 = tile_e + MAX_TILES_;
    int*   tile_cnt  = tile_e + 2 * MAX_TILES_;
    int*   n_tiles   = tile_e + 3 * MAX_TILES_;
    float* scores_f = u1_f;          // overlay: dead before u1/y0/y1/z written
    u16*   G_pl   = (u16*)(ws + 0);  // overlay qa_f/q_f: dead before MoE

    // plane pairs (base as u16*, lo at +E)
    u16* h_pl     = (u16*)(ws + 37377024);
    u16* qa_pl    = (u16*)(ws + 41571328);
    u16* q_pl     = (u16*)(ws + 44717056);
    u16* kvf_pl   = (u16*)(ws + 51008512);
    u16* kvfT_pl  = (u16*)(ws + 52188160);
    u16* qabs_pl  = (u16*)(ws + 53236736);
    u16* sc_pl    = (u16*)(ws + 70013952);
    u16* o2_pl    = (u16*)(ws + 86791168);
    u16* h2_pl    = (u16*)(ws + 90985472);
    u16* u1_pl    = (u16*)(ws + 95179776);
    u16* wqa_pl   = (u16*)(ws + 100946944);
    u16* wqb_pl   = (u16*)(ws + 104092672);
    u16* wkva_pl  = (u16*)(ws + 108811264);
    u16* wkvb_pl  = (u16*)(ws + 110121984);
    u16* wkvb1T_pl= (u16*)(ws + 112219136);
    u16* wo_pl    = (u16*)(ws + 113267712);
    u16* sw1_pl   = (u16*)(ws + 117462016);
    u16* sw3_pl   = (u16*)(ws + 123229184);
    u16* sw2_pl   = (u16*)(ws + 128996352);
    // total: 134,763,520 floats = 539 MB

    // 0. weight conversions to planes
    conv_pl_kernel<<<dim3(3072), 256, 0, stream>>>(wq_a_w, wqa_pl, E_WQA, 3145728);
    conv_pl_kernel<<<dim3(4608), 256, 0, stream>>>(wq_b_w, wqb_pl, E_WQB, 4718592);
    conv_pl_kernel<<<dim3(1152), 256, 0, stream>>>(wkv_a_w, wkva_pl, E_WKVA, 1179648);
    conv_pl_kernel<<<dim3(2048), 256, 0, stream>>>(wkv_b_w, wkvb_pl, E_WKVB, 2097152);
    conv_pl_kernel<<<dim3(4096), 256, 0, stream>>>(wo_w, wo_pl, E_WO, 4194304);
    conv_pl_kernel<<<dim3(5632), 256, 0, stream>>>(s_w1, sw1_pl, E_SW, 5767168);
    conv_pl_kernel<<<dim3(5632), 256, 0, stream>>>(s_w3, sw3_pl, E_SW, 5767168);
    conv_pl_kernel<<<dim3(5632), 256, 0, stream>>>(s_w2, sw2_pl, E_SW, 5767168);
    conv_wkvb1T_kernel<<<dim3(4, 16, 16), 256, 0, stream>>>(wkv_b_w, wkvb1T_pl, E_WKVB1T);

    // 1. h = rms(x) -> planes
    rms_pl_kernel<<<dim3(T_), 256, 0, stream>>>(x, 2048, h_pl, E_H, 2048, attn_nw, 2048, nullptr);

    // 2. qa = h @ wq_a^T + b -> fp32
    gemm_bf_kernel<<<dim3(12, 16, 1), 256, 0, stream>>>(
        h_pl, E_H, 2048, 0, wqa_pl, E_WQA, 2048, 0,
        nullptr, 0, 0, 0, nullptr, 0, 0, 0, 0,
        wq_a_b, nullptr, 0, 0, 0,
        qa_f, nullptr, 0, QLR_, 0, QLR_, 2048);

    // 3. qa = rms(qa) -> planes
    rms_pl_kernel<<<dim3(T_), 256, 0, stream>>>(qa_f, QLR_, qa_pl, E_QA, QLR_, q_norm_w, QLR_, nullptr);

    // 4. q = qa @ wq_b^T + b -> fp32
    gemm_bf_kernel<<<dim3(24, 16, 1), 256, 0, stream>>>(
        qa_pl, E_QA, QLR_, 0, wqb_pl, E_WQB, QLR_, 0,
        nullptr, 0, 0, 0, nullptr, 0, 0, 0, 0,
        wq_b_b, nullptr, 0, 0, 0,
        q_f, nullptr, 0, H_ * QKD_, 0, H_ * QKD_, QLR_);

    // 5. kvf = h @ wkv_a^T + b -> fp32 (N padded 640, lim 576)
    gemm_bf_kernel<<<dim3(5, 16, 1), 256, 0, stream>>>(
        h_pl, E_H, 2048, 0, wkva_pl, E_WKVA, 2048, 0,
        nullptr, 0, 0, 0, nullptr, 0, 0, 0, 0,
        wkv_a_b, nullptr, 0, 0, 0,
        kvf_f, nullptr, 0, KVR_ + ROPE_, 0, KVR_ + ROPE_, 2048);

    // 6. RoPE (fp32 in place)
    {
        int total_q = T_ * H_ * 32;
        rope_kernel<<<dim3((total_q + 255) / 256), 256, 0, stream>>>(
            q_f, cosb, sinb, H_, H_ * QKD_, QKD_, NOPE_, total_q);
        int total_k = T_ * 32;
        rope_kernel<<<dim3((total_k + 255) / 256), 256, 0, stream>>>(
            kvf_f, cosb, sinb, 1, KVR_ + ROPE_, 0, KVR_, total_k);
    }

    // 7. kv_n = rms(kv) fp32 in place
    rms_kernel<<<dim3(T_), 256, 0, stream>>>(kvf_f, kvf_f, kv_norm_w, KVR_,
                                             KVR_ + ROPE_, KVR_ + ROPE_);

    // 8-pre. convert q, kvf to planes; build kvfT planes
    conv_pl_kernel<<<dim3(6144), 256, 0, stream>>>(q_f, q_pl, E_Q, 6291456);
    conv_pl_kernel<<<dim3(1152), 256, 0, stream>>>(kvf_f, kvf_pl, E_KVF, 1179648);
    conv_kvfT_kernel<<<dim3(32, 16, 2), 256, 0, stream>>>(kvf_f, kvfT_pl, E_KVFT);

    // 8. q_abs = q_nope @ wb1 -> planes
    gemm_bf_kernel<<<dim3(4, 16, 16), 256, 0, stream>>>(
        q_pl, E_Q, H_ * QKD_, 192, wkvb1T_pl, E_WKVB1T, 128, (long)512 * 128,
        nullptr, 0, 0, 0, nullptr, 0, 0, 0, 0,
        nullptr, nullptr, 0, 0, 0,
        nullptr, qabs_pl, E_QABS, H_ * KVR_, KVR_, KVR_, NOPE_);

    // 9. attention per batch
    for (int b = 0; b < B_; b++) {
        // QK (K=512) + RoPE term (K2=64) fused -> scores fp32
        gemm_bf_kernel<<<dim3(8, 8, 16), 256, 0, stream>>>(
            qabs_pl + (long)b * S_ * H_ * KVR_, E_QABS, H_ * KVR_, KVR_,
            kvf_pl + (long)b * S_ * (KVR_ + ROPE_), E_KVF, KVR_ + ROPE_, 0,
            q_pl + (long)b * S_ * H_ * QKD_ + NOPE_, E_Q, H_ * QKD_, QKD_,
            kvf_pl + (long)b * S_ * (KVR_ + ROPE_) + KVR_, E_KVF, KVR_ + ROPE_, 0, ROPE_,
            nullptr, nullptr, 0, 0, 0,
            scores_f, nullptr, 0, S_, (long)S_ * S_, S_, KVR_);
        // softmax -> planes
        softmax_pl_kernel<<<dim3(H_ * S_), 256, 0, stream>>>(scores_f, sc_pl, E_SCORES);
        // o = P @ kv_n -> planes (into qabs region)
        gemm_bf_kernel<<<dim3(4, 8, 16), 256, 0, stream>>>(
            sc_pl, E_SCORES, S_, (long)S_ * S_,
            kvfT_pl + (long)b * KVR_ * S_, E_KVFT, S_, 0,
            nullptr, 0, 0, 0, nullptr, 0, 0, 0, 0,
            nullptr, nullptr, 0, 0, 0,
            nullptr, qabs_pl + (long)b * S_ * H_ * KVR_, E_QABS, H_ * KVR_, KVR_, KVR_, S_);
    }

    // 10. o2 = o @ wb2^T -> planes
    gemm_bf_kernel<<<dim3(1, 16, 16), 256, 0, stream>>>(
        qabs_pl, E_QABS, H_ * KVR_, KVR_,
        wkvb_pl + (long)NOPE_ * KVR_, E_WKVB, KVR_, (long)256 * KVR_,
        nullptr, 0, 0, 0, nullptr, 0, 0, 0, 0,
        nullptr, nullptr, 0, 0, 0,
        nullptr, o2_pl, E_O2, H_ * VD_, VD_, VD_, KVR_);

    // 11. x2 = x + o2 @ wo^T + b -> fp32
    gemm_bf_kernel<<<dim3(16, 16, 1), 256, 0, stream>>>(
        o2_pl, E_O2, 2048, 0, wo_pl, E_WO, 2048, 0,
        nullptr, 0, 0, 0, nullptr, 0, 0, 0, 0,
        wo_b, x, 2048, 0, 1,
        x2, nullptr, 0, D_, 0, D_, 2048);

    // 12. h2 = rms(x2) -> planes + fp32
    rms_pl_kernel<<<dim3(T_), 256, 0, stream>>>(x2, 2048, h2_pl, E_H2, 2048, ffn_nw, 2048, h2_f);

    // 13-14. gate + route
    gate_kernel<<<dim3(T_), 256, 0, stream>>>(h2_f, gate_w, gate_b, idx, wts);
    route_kernel<<<dim3(1), 256, 0, stream>>>(idx, wts, slot_te, slot_w,
                                              tile_e, tile_row0, tile_cnt, n_tiles);

    // 15. MoE
    moe_mlp13_kernel<<<dim3(MI_ / 128, MAX_TILES_), 256, 0, stream>>>(
        h2_pl, E_H2, slot_te, tile_e, tile_row0, tile_cnt, n_tiles,
        e_w1, e_b1, e_w3, e_b3, G_pl, E_G);
    moe_mlp2_kernel<<<dim3(D_ / 128, MAX_TILES_), 256, 0, stream>>>(
        G_pl, E_G, slot_te, slot_w, tile_e, tile_row0, tile_cnt, n_tiles,
        e_w2, e_b2, y0, y1);

    // 16. shared MLP (silu fused into s_w3 GEMM epilogue)
    gemm_bf_kernel<<<dim3(22, 16, 1), 256, 0, stream>>>(
        h2_pl, E_H2, 2048, 0, sw1_pl, E_SW, 2048, 0,
        nullptr, 0, 0, 0, nullptr, 0, 0, 0, 0,
        s_b1, nullptr, 0, 0, 0,
        u1_f, nullptr, 0, SMI_, 0, SMI_, 2048);
    gemm_bf_kernel<<<dim3(22, 16, 1), 256, 0, stream>>>(
        h2_pl, E_H2, 2048, 0, sw3_pl, E_SW, 2048, 0,
        nullptr, 0, 0, 0, nullptr, 0, 0, 0, 0,
        s_b3, u1_f, SMI_, 0, 2,
        nullptr, u1_pl, E_U1, SMI_, 0, SMI_, 2048);
    gemm_bf_kernel<<<dim3(16, 16, 1), 256, 0, stream>>>(
        u1_pl, E_U1, SMI_, 0, sw2_pl, E_SW, SMI_, 0,
        nullptr, 0, 0, 0, nullptr, 0, 0, 0, 0,
        s_b2, nullptr, 0, 0, 0,
        z, nullptr, 0, D_, 0, D_, SMI_);

    // 17. out = x2 + h2 + y0 + y1 + z
    {
        long n = (long)T_ * D_;
        final_add_kernel<<<dim3((unsigned)((n + 255) / 256)), 256, 0, stream>>>(
            x2, h2_f, y0, y1, z, (float*)d_out, n);
    }
}